// Round 13
// baseline (468.146 us; speedup 1.0000x reference)
//
#include <hip/hip_runtime.h>
#include <stdint.h>

// ---------------------------------------------------------------------------
// GCastHeterocoder round 13: round-12 structure + dst-sorted edge processing.
// Edge blocks iterate sorted slots (eorder): receiver gathers become a
// near-sequential stream (~21 consecutive receiver rows per block), P writes
// are fully sequential; edge_attr/edge_out move to random full-row access.
// ---------------------------------------------------------------------------

typedef __bf16 bf16x8 __attribute__((ext_vector_type(8)));
typedef float  f32x4  __attribute__((ext_vector_type(4)));

union U16B { uint4 u; bf16x8 v; };
union BFPK { __bf16 h[2]; unsigned int u; };
union BF1  { __bf16 h; unsigned short s; };

__device__ __forceinline__ float silu_f(float x) {
  return x * __builtin_amdgcn_rcpf(1.0f + __expf(-x));
}
__device__ __forceinline__ float bfu2f(unsigned int lo16) {
  return __uint_as_float(lo16 << 16);
}
__device__ __forceinline__ bf16x8 cvt8(float4 a, float4 b) {
  bf16x8 r;
  r[0] = (__bf16)a.x; r[1] = (__bf16)a.y; r[2] = (__bf16)a.z; r[3] = (__bf16)a.w;
  r[4] = (__bf16)b.x; r[5] = (__bf16)b.y; r[6] = (__bf16)b.z; r[7] = (__bf16)b.w;
  return r;
}

// ---------------- fused prep: swizzled weight image + bf16 rows + hist -----
__global__ void prep_kernel(const float* __restrict__ We,
                            const float* __restrict__ Wn,
                            const float* __restrict__ Ws,
                            unsigned short* __restrict__ wimg,
                            const float* __restrict__ sx,
                            unsigned short* __restrict__ sb,
                            const float* __restrict__ rx,
                            unsigned short* __restrict__ rb,
                            int n8s, int n8r,
                            const int* __restrict__ dst,
                            int* __restrict__ counts, int E) {
  int i = blockIdx.x * 256 + threadIdx.x;
  if (i < 6 * 16384) {
    int panel = i >> 14;
    int r = (i >> 7) & 127;
    int csw = i & 127;
    int c_or = ((csw * 2) ^ ((r & 15) << 4)) >> 1;
    float f;
    if (panel < 3)      f = We[r * 384 + panel * 128 + c_or];
    else if (panel < 5) f = Wn[r * 256 + (panel - 3) * 128 + c_or];
    else                f = Ws[r * 128 + c_or];
    BF1 c; c.h = (__bf16)f;
    wimg[i] = c.s;
    return;
  }
  int j = i - 6 * 16384;
  if (j < n8s + n8r) {
    const float* in; unsigned short* out; int idx;
    if (j < n8s) { in = sx; out = sb; idx = j; }
    else         { in = rx; out = rb; idx = j - n8s; }
    float4 a = reinterpret_cast<const float4*>(in)[2 * idx];
    float4 b = reinterpret_cast<const float4*>(in)[2 * idx + 1];
    U16B r8; r8.v = cvt8(a, b);
    reinterpret_cast<uint4*>(out)[idx] = r8.u;
    return;
  }
  int e = j - n8s - n8r;
  if (e < E) atomicAdd(&counts[dst[e]], 1);
}

// ---------------- CSR build ----------------
__global__ void scan1_kernel(const int* __restrict__ counts, int* __restrict__ pre,
                             int* __restrict__ blockSums, int n) {
  __shared__ int sh[256];
  const int t = threadIdx.x;
  const int base = blockIdx.x * 1024 + t * 4;
  int c0 = (base + 0 < n) ? counts[base + 0] : 0;
  int c1 = (base + 1 < n) ? counts[base + 1] : 0;
  int c2 = (base + 2 < n) ? counts[base + 2] : 0;
  int c3 = (base + 3 < n) ? counts[base + 3] : 0;
  int tot = c0 + c1 + c2 + c3;
  sh[t] = tot;
  __syncthreads();
  #pragma unroll
  for (int off = 1; off < 256; off <<= 1) {
    int v = (t >= off) ? sh[t - off] : 0;
    __syncthreads();
    sh[t] += v;
    __syncthreads();
  }
  int excl = sh[t] - tot;
  if (base + 0 < n) pre[base + 0] = excl;
  if (base + 1 < n) pre[base + 1] = excl + c0;
  if (base + 2 < n) pre[base + 2] = excl + c0 + c1;
  if (base + 3 < n) pre[base + 3] = excl + c0 + c1 + c2;
  if (t == 255) blockSums[blockIdx.x] = sh[255];
}

__global__ void scan2_kernel(int* __restrict__ blockSums, int nb) {
  __shared__ int sh[512];
  const int t = threadIdx.x;
  int v = (t < nb) ? blockSums[t] : 0;
  sh[t] = v;
  __syncthreads();
  #pragma unroll
  for (int off = 1; off < 512; off <<= 1) {
    int u = (t >= off) ? sh[t - off] : 0;
    __syncthreads();
    sh[t] += u;
    __syncthreads();
  }
  if (t < nb) blockSums[t] = sh[t] - v;
}

__global__ void scan3_kernel(const int* __restrict__ pre, const int* __restrict__ blockSums,
                             int* __restrict__ offs, int* __restrict__ cursor, int n) {
  int i = blockIdx.x * 256 + threadIdx.x;
  if (i >= n) return;
  int o = pre[i] + blockSums[i >> 10];
  offs[i] = o;
  cursor[i] = o;
}

// eorder[p] = original edge id at sorted position p
__global__ void scatter_kernel(const int* __restrict__ dst, int* __restrict__ cursor,
                               int* __restrict__ eorder, int E) {
  int i = blockIdx.x * 256 + threadIdx.x;
  if (i < E) {
    int p = atomicAdd(&cursor[dst[i]], 1);
    eorder[p] = i;
  }
}

// ---------------------------------------------------------------------------
// v10 MLP core. SORTED: bid indexes sorted slots; perm = eorder maps slot ->
// original edge id (gathers/resid/out use orig; P row = slot, sequential).
// AGGR: 0=none, 2=pk bf16 atomics, 3=P row write.
// ---------------------------------------------------------------------------
template <int KDIM, int AGGR, bool SORTED>
__device__ __forceinline__ void mlp_core(
    unsigned short* smem,
    const unsigned short* __restrict__ s0, const int* __restrict__ i0,
    const unsigned short* __restrict__ s1, const int* __restrict__ i1,
    const float* __restrict__ s2,
    const unsigned short* __restrict__ Wb,
    const float* __restrict__ bias, const float* __restrict__ gamma,
    const float* __restrict__ beta,
    const float* __restrict__ resid,
    float* __restrict__ outp,
    void* aggr, const int* __restrict__ aggr_idx,
    const int* __restrict__ perm,
    int M, int bid) {
  constexpr int NSEG = KDIM / 128;

  const int tid = threadIdx.x;
  const int wid = tid >> 6;
  const int lane = tid & 63;
  const int l15 = lane & 15;
  const int q = lane >> 4;
  const int l31 = lane & 31;
  const int rhalf = lane >> 5;
  const int wrow = bid * 128 + wid * 16;
  const int xm = l15 << 3;

  int rr = wrow + l15;
  if (rr >= M) rr = M - 1;
  int ridx = rr;
  if constexpr (SORTED) ridx = perm[rr];
  const unsigned short* p0 = s0 + (size_t)(i0 ? i0[ridx] : ridx) * 128;
  const unsigned short* p1 = nullptr;
  const float* p2 = nullptr;
  if constexpr (KDIM >= 256) p1 = s1 + (size_t)(i1 ? i1[ridx] : ridx) * 128;
  if constexpr (KDIM >= 384) p2 = s2 + (size_t)ridx * 128;

  auto stageB = [&](int seg) {
    const unsigned short* g = Wb + seg * 16384 + wid * 2048 + lane * 8;
    unsigned short* l = &smem[wid * 2048];
    #pragma unroll
    for (int u = 0; u < 4; ++u) {
      __builtin_amdgcn_global_load_lds(
          (const __attribute__((address_space(1))) unsigned int*)(g + u * 512),
          (__attribute__((address_space(3))) unsigned int*)(l + u * 512),
          16, 0, 0);
    }
  };

  U16B Ac[4], An[4];
  auto loadA = [&](int seg, U16B (&dst_)[4]) {
    #pragma unroll
    for (int k4 = 0; k4 < 4; ++k4) {
      const int kof = k4 * 32 + q * 8;
      if (seg == 0) {
        dst_[k4].u = *reinterpret_cast<const uint4*>(p0 + kof);
      } else if (seg == 1) {
        dst_[k4].u = *reinterpret_cast<const uint4*>(p1 + kof);
      } else {
        const float4* p = reinterpret_cast<const float4*>(p2 + kof);
        dst_[k4].v = cvt8(p[0], p[1]);
      }
    }
  };

  f32x4 acc[8] = {};

  stageB(0);
  loadA(0, Ac);
  __syncthreads();

  #pragma unroll
  for (int seg = 0; seg < NSEG; ++seg) {
    if (seg + 1 < NSEG) loadA(seg + 1, An);
    #pragma unroll
    for (int k4 = 0; k4 < 4; ++k4) {
      #pragma unroll
      for (int n = 0; n < 8; ++n) {
        U16B b;
        b.u = *reinterpret_cast<const uint4*>(
            &smem[(n * 16 + l15) * 128 + ((k4 * 32 + q * 8) ^ xm)]);
        acc[n] = __builtin_amdgcn_mfma_f32_16x16x32_bf16(Ac[k4].v, b.v, acc[n], 0, 0, 0);
      }
    }
    __syncthreads();
    if (seg + 1 < NSEG) {
      stageB(seg + 1);
      __syncthreads();
      #pragma unroll
      for (int k4 = 0; k4 < 4; ++k4) Ac[k4] = An[k4];
    }
  }

  float bia[8];
  #pragma unroll
  for (int n = 0; n < 8; ++n) bia[n] = bias[n * 16 + l15];

  float sum[4] = {0.f, 0.f, 0.f, 0.f};
  float ssq[4] = {0.f, 0.f, 0.f, 0.f};
  #pragma unroll
  for (int n = 0; n < 8; ++n) {
    #pragma unroll
    for (int j = 0; j < 4; ++j) {
      float t = silu_f(silu_f(acc[n][j] + bia[n]));
      acc[n][j] = t;
      sum[j] += t;
      ssq[j] += t * t;
    }
  }
  #pragma unroll
  for (int off = 1; off < 16; off <<= 1) {
    #pragma unroll
    for (int j = 0; j < 4; ++j) {
      sum[j] += __shfl_xor(sum[j], off);
      ssq[j] += __shfl_xor(ssq[j], off);
    }
  }
  float mu[4], rs[4];
  #pragma unroll
  for (int j = 0; j < 4; ++j) {
    mu[j] = sum[j] * (1.0f / 128.0f);
    float var = ssq[j] * (1.0f / 128.0f) - mu[j] * mu[j];
    rs[j] = rsqrtf(var + 1e-5f);
  }
  float gam[8], bet[8];
  #pragma unroll
  for (int n = 0; n < 8; ++n) {
    gam[n] = gamma[n * 16 + l15];
    bet[n] = beta[n * 16 + l15];
  }

  unsigned short* yw = &smem[wid * 2048];

  #pragma unroll
  for (int h = 0; h < 2; ++h) {
    if (h == 1) {
      asm volatile("s_waitcnt lgkmcnt(0)" ::: "memory");
    }
    if ((q >> 1) == h) {
      #pragma unroll
      for (int n = 0; n < 8; ++n) {
        #pragma unroll
        for (int j = 0; j < 4; ++j) {
          float y = (acc[n][j] - mu[j]) * rs[j] * gam[n] + bet[n];
          BF1 c; c.h = (__bf16)y;
          yw[((q & 1) * 4 + j) * 132 + n * 16 + l15] = c.s;
        }
      }
    }
    asm volatile("s_waitcnt lgkmcnt(0)" ::: "memory");

    #pragma unroll
    for (int s = 0; s < 4; ++s) {
      int row8 = 2 * s + rhalf;
      int grow = wrow + 8 * h + row8;
      uint2 w = *reinterpret_cast<const uint2*>(&yw[row8 * 132 + l31 * 4]);
      if (grow < M) {
        int og = grow;
        if constexpr (SORTED) og = perm[grow];
        const f32x4 r4 = *reinterpret_cast<const f32x4*>(resid + (size_t)og * 128 + l31 * 4);
        f32x4 o4;
        o4.x = r4.x + bfu2f(w.x & 0xffffu);
        o4.y = r4.y + bfu2f(w.x >> 16);
        o4.z = r4.z + bfu2f(w.y & 0xffffu);
        o4.w = r4.w + bfu2f(w.y >> 16);
        __builtin_nontemporal_store(o4, reinterpret_cast<f32x4*>(outp + (size_t)og * 128 + l31 * 4));
        if constexpr (AGGR == 3) {
          // SORTED: P row = sorted slot (sequential). Non-sorted: perm=rank.
          int prow = SORTED ? grow : perm[grow];
          *reinterpret_cast<uint2*>((unsigned short*)aggr + (size_t)prow * 128 + l31 * 4) = w;
        } else if constexpr (AGGR == 2) {
          int idx = aggr_idx[grow];
          unsigned short* ar = (unsigned short*)aggr + (size_t)idx * 128 + l31 * 4;
          asm volatile("global_atomic_pk_add_bf16 %0, %1, off" :: "v"(ar), "v"(w.x) : "memory");
          asm volatile("global_atomic_pk_add_bf16 %0, %1, off" :: "v"(ar + 2), "v"(w.y) : "memory");
        }
      }
    }
  }
}

// standalone v10 kernel (fallback tiers)
template <int KDIM, int AGGR>
__global__ __launch_bounds__(512, 6) void mlp_v10_kernel(
    const unsigned short* __restrict__ s0, const int* __restrict__ i0,
    const unsigned short* __restrict__ s1, const int* __restrict__ i1,
    const float* __restrict__ s2,
    const unsigned short* __restrict__ Wb,
    const float* __restrict__ bias, const float* __restrict__ gamma,
    const float* __restrict__ beta,
    const float* __restrict__ resid,
    float* __restrict__ outp,
    void* aggr, const int* __restrict__ aggr_idx,
    const int* __restrict__ prank,
    int M) {
  __shared__ __align__(16) unsigned short smem[16384];
  mlp_core<KDIM, AGGR, false>(smem, s0, i0, s1, i1, s2, Wb, bias, gamma, beta,
                              resid, outp, aggr, aggr_idx, prank, M, blockIdx.x);
}

// ---------------------------------------------------------------------------
// fused edge (dst-sorted slots) + sender launch.
// ---------------------------------------------------------------------------
__global__ __launch_bounds__(512, 6) void fused_es_kernel(
    const unsigned short* __restrict__ sender_b, const int* __restrict__ src,
    const unsigned short* __restrict__ receiver_b, const int* __restrict__ dst,
    const float* __restrict__ edge_attr,
    const unsigned short* __restrict__ We_b,
    const float* __restrict__ be, const float* __restrict__ ge,
    const float* __restrict__ bbe,
    float* __restrict__ edge_out,
    unsigned short* __restrict__ P, const int* __restrict__ eorder,
    const unsigned short* __restrict__ Ws_b,
    const float* __restrict__ bs, const float* __restrict__ gs,
    const float* __restrict__ bbs,
    const float* __restrict__ sender_x, float* __restrict__ sender_out,
    int E, int NS, int gridE) {
  __shared__ __align__(16) unsigned short smem[16384];
  const int b = blockIdx.x;
  if (b < gridE) {
    mlp_core<384, 3, true>(smem, sender_b, src, receiver_b, dst, edge_attr,
                           We_b, be, ge, bbe, edge_attr, edge_out,
                           P, nullptr, eorder, E, b);
  } else {
    mlp_core<128, 0, false>(smem, sender_b, nullptr, nullptr, nullptr, nullptr,
                            Ws_b, bs, gs, bbs, sender_x, sender_out,
                            nullptr, nullptr, nullptr, NS, b - gridE);
  }
}

// ---------------------------------------------------------------------------
// node MLP with fused CSR segment-sum (P slices are contiguous sorted slots).
// ---------------------------------------------------------------------------
__global__ __launch_bounds__(512, 4) void node_csr_kernel(
    const unsigned short* __restrict__ s0,           // receiver_b
    const unsigned short* __restrict__ P,
    const int* __restrict__ offs, const int* __restrict__ counts,
    const unsigned short* __restrict__ Wb,           // 2 panels (Wn)
    const float* __restrict__ bias, const float* __restrict__ gamma,
    const float* __restrict__ beta,
    const float* __restrict__ resid, float* __restrict__ outp,
    int M) {
  __shared__ __align__(16) unsigned short smem[16384];

  const int tid = threadIdx.x;
  const int wid = tid >> 6;
  const int lane = tid & 63;
  const int l15 = lane & 15;
  const int q = lane >> 4;
  const int l31 = lane & 31;
  const int rhalf = lane >> 5;
  const int wrow = blockIdx.x * 128 + wid * 16;
  const int xm = l15 << 3;

  int rr = wrow + l15;
  if (rr >= M) rr = M - 1;
  const unsigned short* p0 = s0 + (size_t)rr * 128;

  auto stageB = [&](int seg) {
    const unsigned short* g = Wb + seg * 16384 + wid * 2048 + lane * 8;
    unsigned short* l = &smem[wid * 2048];
    #pragma unroll
    for (int u = 0; u < 4; ++u) {
      __builtin_amdgcn_global_load_lds(
          (const __attribute__((address_space(1))) unsigned int*)(g + u * 512),
          (__attribute__((address_space(3))) unsigned int*)(l + u * 512),
          16, 0, 0);
    }
  };

  U16B Ac[4];
  #pragma unroll
  for (int k4 = 0; k4 < 4; ++k4)
    Ac[k4].u = *reinterpret_cast<const uint4*>(p0 + k4 * 32 + q * 8);

  stageB(0);
  __syncthreads();

  f32x4 acc[8] = {};
  #pragma unroll
  for (int k4 = 0; k4 < 4; ++k4) {
    #pragma unroll
    for (int n = 0; n < 8; ++n) {
      U16B b;
      b.u = *reinterpret_cast<const uint4*>(
          &smem[(n * 16 + l15) * 128 + ((k4 * 32 + q * 8) ^ xm)]);
      acc[n] = __builtin_amdgcn_mfma_f32_16x16x32_bf16(Ac[k4].v, b.v, acc[n], 0, 0, 0);
    }
  }
  __syncthreads();
  stageB(1);

  {
    int beg = offs[rr];
    int cnt = counts[rr];
    float a32[32];
    #pragma unroll
    for (int t = 0; t < 32; ++t) a32[t] = 0.f;
    const unsigned short* prow = P + (size_t)beg * 128;
    for (int k = 0; k < cnt; ++k) {
      #pragma unroll
      for (int k4 = 0; k4 < 4; ++k4) {
        uint4 w = *reinterpret_cast<const uint4*>(prow + k4 * 32 + q * 8);
        a32[k4 * 8 + 0] += bfu2f(w.x & 0xffffu);
        a32[k4 * 8 + 1] += bfu2f(w.x >> 16);
        a32[k4 * 8 + 2] += bfu2f(w.y & 0xffffu);
        a32[k4 * 8 + 3] += bfu2f(w.y >> 16);
        a32[k4 * 8 + 4] += bfu2f(w.z & 0xffffu);
        a32[k4 * 8 + 5] += bfu2f(w.z >> 16);
        a32[k4 * 8 + 6] += bfu2f(w.w & 0xffffu);
        a32[k4 * 8 + 7] += bfu2f(w.w >> 16);
      }
      prow += 128;
    }
    #pragma unroll
    for (int k4 = 0; k4 < 4; ++k4) {
      #pragma unroll
      for (int j = 0; j < 8; ++j)
        Ac[k4].v[j] = (__bf16)a32[k4 * 8 + j];
    }
  }
  __syncthreads();

  #pragma unroll
  for (int k4 = 0; k4 < 4; ++k4) {
    #pragma unroll
    for (int n = 0; n < 8; ++n) {
      U16B b;
      b.u = *reinterpret_cast<const uint4*>(
          &smem[(n * 16 + l15) * 128 + ((k4 * 32 + q * 8) ^ xm)]);
      acc[n] = __builtin_amdgcn_mfma_f32_16x16x32_bf16(Ac[k4].v, b.v, acc[n], 0, 0, 0);
    }
  }
  __syncthreads();

  float bia[8];
  #pragma unroll
  for (int n = 0; n < 8; ++n) bia[n] = bias[n * 16 + l15];

  float sum[4] = {0.f, 0.f, 0.f, 0.f};
  float ssq[4] = {0.f, 0.f, 0.f, 0.f};
  #pragma unroll
  for (int n = 0; n < 8; ++n) {
    #pragma unroll
    for (int j = 0; j < 4; ++j) {
      float t = silu_f(silu_f(acc[n][j] + bia[n]));
      acc[n][j] = t;
      sum[j] += t;
      ssq[j] += t * t;
    }
  }
  #pragma unroll
  for (int off = 1; off < 16; off <<= 1) {
    #pragma unroll
    for (int j = 0; j < 4; ++j) {
      sum[j] += __shfl_xor(sum[j], off);
      ssq[j] += __shfl_xor(ssq[j], off);
    }
  }
  float mu[4], rs[4];
  #pragma unroll
  for (int j = 0; j < 4; ++j) {
    mu[j] = sum[j] * (1.0f / 128.0f);
    float var = ssq[j] * (1.0f / 128.0f) - mu[j] * mu[j];
    rs[j] = rsqrtf(var + 1e-5f);
  }
  float gam[8], bet[8];
  #pragma unroll
  for (int n = 0; n < 8; ++n) {
    gam[n] = gamma[n * 16 + l15];
    bet[n] = beta[n * 16 + l15];
  }

  unsigned short* yw = &smem[wid * 2048];

  #pragma unroll
  for (int h = 0; h < 2; ++h) {
    if (h == 1) {
      asm volatile("s_waitcnt lgkmcnt(0)" ::: "memory");
    }
    if ((q >> 1) == h) {
      #pragma unroll
      for (int n = 0; n < 8; ++n) {
        #pragma unroll
        for (int j = 0; j < 4; ++j) {
          float y = (acc[n][j] - mu[j]) * rs[j] * gam[n] + bet[n];
          BF1 c; c.h = (__bf16)y;
          yw[((q & 1) * 4 + j) * 132 + n * 16 + l15] = c.s;
        }
      }
    }
    asm volatile("s_waitcnt lgkmcnt(0)" ::: "memory");

    #pragma unroll
    for (int s = 0; s < 4; ++s) {
      int row8 = 2 * s + rhalf;
      int grow = wrow + 8 * h + row8;
      uint2 w = *reinterpret_cast<const uint2*>(&yw[row8 * 132 + l31 * 4]);
      if (grow < M) {
        const f32x4 r4 = *reinterpret_cast<const f32x4*>(resid + (size_t)grow * 128 + l31 * 4);
        f32x4 o4;
        o4.x = r4.x + bfu2f(w.x & 0xffffu);
        o4.y = r4.y + bfu2f(w.x >> 16);
        o4.z = r4.z + bfu2f(w.y & 0xffffu);
        o4.w = r4.w + bfu2f(w.y >> 16);
        __builtin_nontemporal_store(o4, reinterpret_cast<f32x4*>(outp + (size_t)grow * 128 + l31 * 4));
      }
    }
  }
}

// ---------------------------------------------------------------------------
// fallback kernel (fp32 features, fp32 atomics) for small-ws tier.
// ---------------------------------------------------------------------------
template <int KDIM>
__global__ __launch_bounds__(512, 4) void mlp_fb_kernel(
    const float* __restrict__ s0, const int* __restrict__ i0,
    const float* __restrict__ s1, const int* __restrict__ i1,
    const float* __restrict__ s2,
    const unsigned short* __restrict__ Wb,
    const float* __restrict__ bias, const float* __restrict__ gamma,
    const float* __restrict__ beta,
    const float* __restrict__ resid,
    float* __restrict__ outp,
    float* aggr, const int* __restrict__ aggr_idx,
    int M) {
  constexpr int NSEG = KDIM / 128;
  __shared__ __align__(16) unsigned short smem[2][16384];
  const int tid = threadIdx.x;
  const int wid = tid >> 6;
  const int lane = tid & 63;
  const int l15 = lane & 15;
  const int q = lane >> 4;
  const int l31 = lane & 31;
  const int rhalf = lane >> 5;
  const int wrow = blockIdx.x * 128 + wid * 16;
  const int xm = l15 << 3;

  int rr = wrow + l15;
  if (rr >= M) rr = M - 1;
  const float* p0 = s0 + (size_t)(i0 ? i0[rr] : rr) * 128;
  const float* p1 = (KDIM >= 256) ? (s1 + (size_t)(i1 ? i1[rr] : rr) * 128) : nullptr;
  const float* p2 = (KDIM >= 384) ? (s2 + (size_t)rr * 128) : nullptr;

  auto stageB = [&](int seg, int buf) {
    const unsigned short* g = Wb + seg * 16384 + wid * 2048 + lane * 8;
    unsigned short* l = &smem[buf][wid * 2048];
    #pragma unroll
    for (int u = 0; u < 4; ++u) {
      __builtin_amdgcn_global_load_lds(
          (const __attribute__((address_space(1))) unsigned int*)(g + u * 512),
          (__attribute__((address_space(3))) unsigned int*)(l + u * 512),
          16, 0, 0);
    }
  };

  stageB(0, 0);
  f32x4 acc[8] = {};
  __syncthreads();
  int cur = 0;
  #pragma unroll
  for (int seg = 0; seg < NSEG; ++seg) {
    if (seg + 1 < NSEG) stageB(seg + 1, cur ^ 1);
    const float* base = (seg == 0) ? p0 : ((seg == 1) ? p1 : p2);
    #pragma unroll
    for (int k4 = 0; k4 < 4; ++k4) {
      const float4* pp = reinterpret_cast<const float4*>(base + k4 * 32 + q * 8);
      U16B a; a.v = cvt8(pp[0], pp[1]);
      #pragma unroll
      for (int n = 0; n < 8; ++n) {
        U16B b;
        b.u = *reinterpret_cast<const uint4*>(
            &smem[cur][(n * 16 + l15) * 128 + ((k4 * 32 + q * 8) ^ xm)]);
        acc[n] = __builtin_amdgcn_mfma_f32_16x16x32_bf16(a.v, b.v, acc[n], 0, 0, 0);
      }
    }
    __syncthreads();
    if (seg + 1 < NSEG) cur ^= 1;
  }

  unsigned short* yw = &smem[0][0] + wid * (16 * 132);
  float bia[8];
  #pragma unroll
  for (int n = 0; n < 8; ++n) bia[n] = bias[n * 16 + l15];
  float sum[4] = {0.f, 0.f, 0.f, 0.f}, ssq[4] = {0.f, 0.f, 0.f, 0.f};
  #pragma unroll
  for (int n = 0; n < 8; ++n)
    #pragma unroll
    for (int j = 0; j < 4; ++j) {
      float t = silu_f(silu_f(acc[n][j] + bia[n]));
      acc[n][j] = t; sum[j] += t; ssq[j] += t * t;
    }
  #pragma unroll
  for (int off = 1; off < 16; off <<= 1)
    #pragma unroll
    for (int j = 0; j < 4; ++j) {
      sum[j] += __shfl_xor(sum[j], off);
      ssq[j] += __shfl_xor(ssq[j], off);
    }
  float mu[4], rs[4];
  #pragma unroll
  for (int j = 0; j < 4; ++j) {
    mu[j] = sum[j] * (1.0f / 128.0f);
    float var = ssq[j] * (1.0f / 128.0f) - mu[j] * mu[j];
    rs[j] = rsqrtf(var + 1e-5f);
  }
  float gam[8], bet[8];
  #pragma unroll
  for (int n = 0; n < 8; ++n) { gam[n] = gamma[n * 16 + l15]; bet[n] = beta[n * 16 + l15]; }
  #pragma unroll
  for (int n = 0; n < 8; ++n)
    #pragma unroll
    for (int j = 0; j < 4; ++j) {
      float y = (acc[n][j] - mu[j]) * rs[j] * gam[n] + bet[n];
      BF1 c; c.h = (__bf16)y;
      yw[(q * 4 + j) * 132 + n * 16 + l15] = c.s;
    }
  asm volatile("s_waitcnt lgkmcnt(0)" ::: "memory");
  #pragma unroll
  for (int s = 0; s < 8; ++s) {
    int row16 = 2 * s + rhalf;
    int grow = wrow + row16;
    uint2 w = *reinterpret_cast<const uint2*>(&yw[row16 * 132 + l31 * 4]);
    if (grow < M) {
      const f32x4 r4 = *reinterpret_cast<const f32x4*>(resid + (size_t)grow * 128 + l31 * 4);
      f32x4 o4;
      o4.x = r4.x + bfu2f(w.x & 0xffffu);
      o4.y = r4.y + bfu2f(w.x >> 16);
      o4.z = r4.z + bfu2f(w.y & 0xffffu);
      o4.w = r4.w + bfu2f(w.y >> 16);
      __builtin_nontemporal_store(o4, reinterpret_cast<f32x4*>(outp + (size_t)grow * 128 + l31 * 4));
      if (aggr) {
        int idx = aggr_idx[grow];
        float* ar = aggr + (size_t)idx * 128 + l31 * 4;
        atomicAdd(ar + 0, bfu2f(w.x & 0xffffu));
        atomicAdd(ar + 1, bfu2f(w.x >> 16));
        atomicAdd(ar + 2, bfu2f(w.y & 0xffffu));
        atomicAdd(ar + 3, bfu2f(w.y >> 16));
      }
    }
  }
}

extern "C" void kernel_launch(void* const* d_in, const int* in_sizes, int n_in,
                              void* d_out, int out_size, void* d_ws, size_t ws_size,
                              hipStream_t stream) {
  const float* sender_x   = (const float*)d_in[0];
  const float* receiver_x = (const float*)d_in[1];
  const int*   edge_index = (const int*)d_in[2];
  const float* edge_attr  = (const float*)d_in[3];
  const float* We  = (const float*)d_in[4];
  const float* be  = (const float*)d_in[5];
  const float* ge  = (const float*)d_in[6];
  const float* bbe = (const float*)d_in[7];
  const float* Wn  = (const float*)d_in[8];
  const float* bn  = (const float*)d_in[9];
  const float* gn  = (const float*)d_in[10];
  const float* bbn = (const float*)d_in[11];
  const float* Ws  = (const float*)d_in[12];
  const float* bs  = (const float*)d_in[13];
  const float* gs  = (const float*)d_in[14];
  const float* bbs = (const float*)d_in[15];

  const int D  = 128;
  const int NS = in_sizes[0] / D;
  const int NR = in_sizes[1] / D;
  const int E  = in_sizes[2] / 2;

  const int* src = edge_index;
  const int* dst = edge_index + E;

  float* out          = (float*)d_out;
  float* sender_out   = out;
  float* receiver_out = out + (size_t)NS * D;
  float* edge_out     = out + (size_t)(NS + NR) * D;

  const size_t welems = 6 * 16384;
  unsigned short* We_b = (unsigned short*)d_ws;          // panels 0..2
  unsigned short* Wn_b = We_b + 3 * 16384;               // panels 3..4
  unsigned short* Ws_b = We_b + 5 * 16384;               // panel 5
  unsigned short* sender_b   = We_b + welems;
  unsigned short* receiver_b = sender_b + (size_t)NS * D;
  unsigned short* aggr_b     = receiver_b + (size_t)NR * D;  // tier-1 only
  unsigned short* P_b        = aggr_b + (size_t)NR * D;
  int* counts    = (int*)(P_b + (size_t)E * D);
  int* pre       = counts + NR;
  int* offs      = pre + NR;
  int* cursor    = offs + NR;
  int* blockSums = cursor + NR;
  int* eorder    = blockSums + 512;

  const int nScanBlocks = (NR + 1023) / 1024;
  const size_t needCSR = 2 * (welems + (size_t)(NS + 2 * NR) * D + (size_t)E * D)
                       + 4 * (4 * (size_t)NR + 512 + (size_t)E);
  const size_t needA = (welems + (size_t)(NS + 2 * NR) * D) * 2;

  int tier;
  if (ws_size >= needCSR && nScanBlocks <= 512) tier = 0;
  else if (ws_size >= needA) tier = 1;
  else tier = 2;

  const int gridE = (E + 127) / 128;
  const int gridR = (NR + 127) / 128;
  const int gridS = (NS + 127) / 128;
  const int n8s = NS * D / 8, n8r = NR * D / 8;

  if (tier == 0) {
    (void)hipMemsetAsync(counts, 0, (size_t)NR * 4, stream);
    const int prepItems = (int)welems + n8s + n8r + E;
    prep_kernel<<<(prepItems + 255) / 256, 256, 0, stream>>>(
        We, Wn, Ws, We_b, sender_x, sender_b, receiver_x, receiver_b,
        n8s, n8r, dst, counts, E);

    scan1_kernel<<<nScanBlocks, 256, 0, stream>>>(counts, pre, blockSums, NR);
    scan2_kernel<<<1, 512, 0, stream>>>(blockSums, nScanBlocks);
    scan3_kernel<<<(NR + 255) / 256, 256, 0, stream>>>(pre, blockSums, offs, cursor, NR);
    scatter_kernel<<<(E + 255) / 256, 256, 0, stream>>>(dst, cursor, eorder, E);

    // edge MLP (dst-sorted slots) + sender MLP in one launch
    fused_es_kernel<<<gridE + gridS, 512, 0, stream>>>(
        sender_b, src, receiver_b, dst, edge_attr,
        We_b, be, ge, bbe, edge_out, P_b, eorder,
        Ws_b, bs, gs, bbs, sender_x, sender_out,
        E, NS, gridE);

    // node MLP with fused CSR segment-sum
    node_csr_kernel<<<gridR, 512, 0, stream>>>(
        receiver_b, P_b, offs, counts,
        Wn_b, bn, gn, bbn, receiver_x, receiver_out, NR);
  } else if (tier == 1) {
    const int prepItems = (int)welems + n8s + n8r;
    prep_kernel<<<(prepItems + 255) / 256, 256, 0, stream>>>(
        We, Wn, Ws, We_b, sender_x, sender_b, receiver_x, receiver_b,
        n8s, n8r, nullptr, nullptr, 0);
    (void)hipMemsetAsync(aggr_b, 0, (size_t)NR * D * 2, stream);

    mlp_v10_kernel<384, 2><<<gridE, 512, 0, stream>>>(
        sender_b, src, receiver_b, dst, edge_attr,
        We_b, be, ge, bbe, edge_attr, edge_out, aggr_b, dst, nullptr, E);

    mlp_v10_kernel<256, 0><<<gridR, 512, 0, stream>>>(
        receiver_b, nullptr, aggr_b, nullptr, nullptr,
        Wn_b, bn, gn, bbn, receiver_x, receiver_out, nullptr, nullptr, nullptr, NR);

    mlp_v10_kernel<128, 0><<<gridS, 512, 0, stream>>>(
        sender_b, nullptr, nullptr, nullptr, nullptr,
        Ws_b, bs, gs, bbs, sender_x, sender_out, nullptr, nullptr, nullptr, NS);
  } else {
    prep_kernel<<<(int)((welems + 255) / 256), 256, 0, stream>>>(
        We, Wn, Ws, We_b, nullptr, nullptr, nullptr, nullptr, 0, 0,
        nullptr, nullptr, 0);
    (void)hipMemsetAsync(receiver_out, 0, (size_t)NR * D * sizeof(float), stream);

    mlp_fb_kernel<384><<<gridE, 512, 0, stream>>>(
        sender_x, src, receiver_x, dst, edge_attr,
        We_b, be, ge, bbe, edge_attr, edge_out, receiver_out, dst, E);

    mlp_fb_kernel<256><<<gridR, 512, 0, stream>>>(
        receiver_x, nullptr, receiver_out, nullptr, nullptr,
        Wn_b, bn, gn, bbn, receiver_x, receiver_out, nullptr, nullptr, NR);

    mlp_fb_kernel<128><<<gridS, 512, 0, stream>>>(
        sender_x, nullptr, nullptr, nullptr, nullptr,
        Ws_b, bs, gs, bbs, sender_x, sender_out, nullptr, nullptr, NS);
  }
}

// Round 14
// 453.175 us; speedup vs baseline: 1.0330x; 1.0330x over previous
//
#include <hip/hip_runtime.h>
#include <stdint.h>

// ---------------------------------------------------------------------------
// GCastHeterocoder FINAL (= round 12, best known 451 us; round-13 dst-sorted
// variant regressed and is reverted). Structure:
//   prep (swizzled bf16 weight image + bf16 node rows + dst histogram)
//   -> CSR scan/scatter -> fused edge+sender MFMA MLP (rank-placed P rows)
//   -> node MLP with fused CSR segment-sum.
// Empirical roofline: 3.5-3.8 TB/s effective for the stream+random-gather
// access mix, traffic at hand-computed minimum.
// ---------------------------------------------------------------------------

typedef __bf16 bf16x8 __attribute__((ext_vector_type(8)));
typedef float  f32x4  __attribute__((ext_vector_type(4)));

union U16B { uint4 u; bf16x8 v; };
union BFPK { __bf16 h[2]; unsigned int u; };
union BF1  { __bf16 h; unsigned short s; };

__device__ __forceinline__ float silu_f(float x) {
  return x * __builtin_amdgcn_rcpf(1.0f + __expf(-x));
}
__device__ __forceinline__ float bfu2f(unsigned int lo16) {
  return __uint_as_float(lo16 << 16);
}
__device__ __forceinline__ bf16x8 cvt8(float4 a, float4 b) {
  bf16x8 r;
  r[0] = (__bf16)a.x; r[1] = (__bf16)a.y; r[2] = (__bf16)a.z; r[3] = (__bf16)a.w;
  r[4] = (__bf16)b.x; r[5] = (__bf16)b.y; r[6] = (__bf16)b.z; r[7] = (__bf16)b.w;
  return r;
}

// ---------------- fused prep: swizzled weight image + bf16 rows + hist -----
// Weight image: 6 panels [128 r][128 c]; row r byte b holds W[r][(b^((r&15)<<4))/2].
__global__ void prep_kernel(const float* __restrict__ We,
                            const float* __restrict__ Wn,
                            const float* __restrict__ Ws,
                            unsigned short* __restrict__ wimg,
                            const float* __restrict__ sx,
                            unsigned short* __restrict__ sb,
                            const float* __restrict__ rx,
                            unsigned short* __restrict__ rb,
                            int n8s, int n8r,
                            const int* __restrict__ dst,
                            int* __restrict__ counts, int E) {
  int i = blockIdx.x * 256 + threadIdx.x;
  if (i < 6 * 16384) {
    int panel = i >> 14;
    int r = (i >> 7) & 127;
    int csw = i & 127;
    int c_or = ((csw * 2) ^ ((r & 15) << 4)) >> 1;
    float f;
    if (panel < 3)      f = We[r * 384 + panel * 128 + c_or];
    else if (panel < 5) f = Wn[r * 256 + (panel - 3) * 128 + c_or];
    else                f = Ws[r * 128 + c_or];
    BF1 c; c.h = (__bf16)f;
    wimg[i] = c.s;
    return;
  }
  int j = i - 6 * 16384;
  if (j < n8s + n8r) {
    const float* in; unsigned short* out; int idx;
    if (j < n8s) { in = sx; out = sb; idx = j; }
    else         { in = rx; out = rb; idx = j - n8s; }
    float4 a = reinterpret_cast<const float4*>(in)[2 * idx];
    float4 b = reinterpret_cast<const float4*>(in)[2 * idx + 1];
    U16B r8; r8.v = cvt8(a, b);
    reinterpret_cast<uint4*>(out)[idx] = r8.u;
    return;
  }
  int e = j - n8s - n8r;
  if (e < E) atomicAdd(&counts[dst[e]], 1);
}

// ---------------- CSR build ----------------
__global__ void scan1_kernel(const int* __restrict__ counts, int* __restrict__ pre,
                             int* __restrict__ blockSums, int n) {
  __shared__ int sh[256];
  const int t = threadIdx.x;
  const int base = blockIdx.x * 1024 + t * 4;
  int c0 = (base + 0 < n) ? counts[base + 0] : 0;
  int c1 = (base + 1 < n) ? counts[base + 1] : 0;
  int c2 = (base + 2 < n) ? counts[base + 2] : 0;
  int c3 = (base + 3 < n) ? counts[base + 3] : 0;
  int tot = c0 + c1 + c2 + c3;
  sh[t] = tot;
  __syncthreads();
  #pragma unroll
  for (int off = 1; off < 256; off <<= 1) {
    int v = (t >= off) ? sh[t - off] : 0;
    __syncthreads();
    sh[t] += v;
    __syncthreads();
  }
  int excl = sh[t] - tot;
  if (base + 0 < n) pre[base + 0] = excl;
  if (base + 1 < n) pre[base + 1] = excl + c0;
  if (base + 2 < n) pre[base + 2] = excl + c0 + c1;
  if (base + 3 < n) pre[base + 3] = excl + c0 + c1 + c2;
  if (t == 255) blockSums[blockIdx.x] = sh[255];
}

__global__ void scan2_kernel(int* __restrict__ blockSums, int nb) {
  __shared__ int sh[512];
  const int t = threadIdx.x;
  int v = (t < nb) ? blockSums[t] : 0;
  sh[t] = v;
  __syncthreads();
  #pragma unroll
  for (int off = 1; off < 512; off <<= 1) {
    int u = (t >= off) ? sh[t - off] : 0;
    __syncthreads();
    sh[t] += u;
    __syncthreads();
  }
  if (t < nb) blockSums[t] = sh[t] - v;
}

__global__ void scan3_kernel(const int* __restrict__ pre, const int* __restrict__ blockSums,
                             int* __restrict__ offs, int* __restrict__ cursor, int n) {
  int i = blockIdx.x * 256 + threadIdx.x;
  if (i >= n) return;
  int o = pre[i] + blockSums[i >> 10];
  offs[i] = o;
  cursor[i] = o;
}

// rank[e] = sorted position of edge e (dst-sorted)
__global__ void scatter_kernel(const int* __restrict__ dst, int* __restrict__ cursor,
                               int* __restrict__ rank, int E) {
  int i = blockIdx.x * 256 + threadIdx.x;
  if (i < E) {
    int p = atomicAdd(&cursor[dst[i]], 1);
    rank[i] = p;
  }
}

// ---------------------------------------------------------------------------
// v10 MLP core as a device function (smem passed in; bid replaces blockIdx).
// AGGR: 0=none, 2=pk bf16 atomics, 3=P row at prank[grow].
// ---------------------------------------------------------------------------
template <int KDIM, int AGGR>
__device__ __forceinline__ void mlp_core(
    unsigned short* smem,
    const unsigned short* __restrict__ s0, const int* __restrict__ i0,
    const unsigned short* __restrict__ s1, const int* __restrict__ i1,
    const float* __restrict__ s2,
    const unsigned short* __restrict__ Wb,
    const float* __restrict__ bias, const float* __restrict__ gamma,
    const float* __restrict__ beta,
    const float* __restrict__ resid,
    float* __restrict__ outp,
    void* aggr, const int* __restrict__ aggr_idx,
    const int* __restrict__ prank,
    int M, int bid) {
  constexpr int NSEG = KDIM / 128;

  const int tid = threadIdx.x;
  const int wid = tid >> 6;
  const int lane = tid & 63;
  const int l15 = lane & 15;
  const int q = lane >> 4;
  const int l31 = lane & 31;
  const int rhalf = lane >> 5;
  const int wrow = bid * 128 + wid * 16;
  const int xm = l15 << 3;

  int rr = wrow + l15;
  if (rr >= M) rr = M - 1;
  const unsigned short* p0 = s0 + (size_t)(i0 ? i0[rr] : rr) * 128;
  const unsigned short* p1 = nullptr;
  const float* p2 = nullptr;
  if constexpr (KDIM >= 256) p1 = s1 + (size_t)(i1 ? i1[rr] : rr) * 128;
  if constexpr (KDIM >= 384) p2 = s2 + (size_t)rr * 128;

  auto stageB = [&](int seg) {
    const unsigned short* g = Wb + seg * 16384 + wid * 2048 + lane * 8;
    unsigned short* l = &smem[wid * 2048];
    #pragma unroll
    for (int u = 0; u < 4; ++u) {
      __builtin_amdgcn_global_load_lds(
          (const __attribute__((address_space(1))) unsigned int*)(g + u * 512),
          (__attribute__((address_space(3))) unsigned int*)(l + u * 512),
          16, 0, 0);
    }
  };

  U16B Ac[4], An[4];
  auto loadA = [&](int seg, U16B (&dst)[4]) {
    #pragma unroll
    for (int k4 = 0; k4 < 4; ++k4) {
      const int kof = k4 * 32 + q * 8;
      if (seg == 0) {
        dst[k4].u = *reinterpret_cast<const uint4*>(p0 + kof);
      } else if (seg == 1) {
        dst[k4].u = *reinterpret_cast<const uint4*>(p1 + kof);
      } else {
        const float4* p = reinterpret_cast<const float4*>(p2 + kof);
        dst[k4].v = cvt8(p[0], p[1]);
      }
    }
  };

  f32x4 acc[8] = {};

  stageB(0);
  loadA(0, Ac);
  __syncthreads();

  #pragma unroll
  for (int seg = 0; seg < NSEG; ++seg) {
    if (seg + 1 < NSEG) loadA(seg + 1, An);
    #pragma unroll
    for (int k4 = 0; k4 < 4; ++k4) {
      #pragma unroll
      for (int n = 0; n < 8; ++n) {
        U16B b;
        b.u = *reinterpret_cast<const uint4*>(
            &smem[(n * 16 + l15) * 128 + ((k4 * 32 + q * 8) ^ xm)]);
        acc[n] = __builtin_amdgcn_mfma_f32_16x16x32_bf16(Ac[k4].v, b.v, acc[n], 0, 0, 0);
      }
    }
    __syncthreads();
    if (seg + 1 < NSEG) {
      stageB(seg + 1);
      __syncthreads();
      #pragma unroll
      for (int k4 = 0; k4 < 4; ++k4) Ac[k4] = An[k4];
    }
  }

  float bia[8];
  #pragma unroll
  for (int n = 0; n < 8; ++n) bia[n] = bias[n * 16 + l15];

  float sum[4] = {0.f, 0.f, 0.f, 0.f};
  float ssq[4] = {0.f, 0.f, 0.f, 0.f};
  #pragma unroll
  for (int n = 0; n < 8; ++n) {
    #pragma unroll
    for (int j = 0; j < 4; ++j) {
      float t = silu_f(silu_f(acc[n][j] + bia[n]));
      acc[n][j] = t;
      sum[j] += t;
      ssq[j] += t * t;
    }
  }
  #pragma unroll
  for (int off = 1; off < 16; off <<= 1) {
    #pragma unroll
    for (int j = 0; j < 4; ++j) {
      sum[j] += __shfl_xor(sum[j], off);
      ssq[j] += __shfl_xor(ssq[j], off);
    }
  }
  float mu[4], rs[4];
  #pragma unroll
  for (int j = 0; j < 4; ++j) {
    mu[j] = sum[j] * (1.0f / 128.0f);
    float var = ssq[j] * (1.0f / 128.0f) - mu[j] * mu[j];
    rs[j] = rsqrtf(var + 1e-5f);
  }
  float gam[8], bet[8];
  #pragma unroll
  for (int n = 0; n < 8; ++n) {
    gam[n] = gamma[n * 16 + l15];
    bet[n] = beta[n * 16 + l15];
  }

  unsigned short* yw = &smem[wid * 2048];

  #pragma unroll
  for (int h = 0; h < 2; ++h) {
    if (h == 1) {
      asm volatile("s_waitcnt lgkmcnt(0)" ::: "memory");
    }
    if ((q >> 1) == h) {
      #pragma unroll
      for (int n = 0; n < 8; ++n) {
        #pragma unroll
        for (int j = 0; j < 4; ++j) {
          float y = (acc[n][j] - mu[j]) * rs[j] * gam[n] + bet[n];
          BF1 c; c.h = (__bf16)y;
          yw[((q & 1) * 4 + j) * 132 + n * 16 + l15] = c.s;
        }
      }
    }
    asm volatile("s_waitcnt lgkmcnt(0)" ::: "memory");

    #pragma unroll
    for (int s = 0; s < 4; ++s) {
      int row8 = 2 * s + rhalf;
      int grow = wrow + 8 * h + row8;
      uint2 w = *reinterpret_cast<const uint2*>(&yw[row8 * 132 + l31 * 4]);
      if (grow < M) {
        const f32x4 r4 = *reinterpret_cast<const f32x4*>(resid + (size_t)grow * 128 + l31 * 4);
        f32x4 o4;
        o4.x = r4.x + bfu2f(w.x & 0xffffu);
        o4.y = r4.y + bfu2f(w.x >> 16);
        o4.z = r4.z + bfu2f(w.y & 0xffffu);
        o4.w = r4.w + bfu2f(w.y >> 16);
        __builtin_nontemporal_store(o4, reinterpret_cast<f32x4*>(outp + (size_t)grow * 128 + l31 * 4));
        if constexpr (AGGR == 3) {
          int prow = prank[grow];
          *reinterpret_cast<uint2*>((unsigned short*)aggr + (size_t)prow * 128 + l31 * 4) = w;
        } else if constexpr (AGGR == 2) {
          int idx = aggr_idx[grow];
          unsigned short* ar = (unsigned short*)aggr + (size_t)idx * 128 + l31 * 4;
          asm volatile("global_atomic_pk_add_bf16 %0, %1, off" :: "v"(ar), "v"(w.x) : "memory");
          asm volatile("global_atomic_pk_add_bf16 %0, %1, off" :: "v"(ar + 2), "v"(w.y) : "memory");
        }
      }
    }
  }
}

// standalone v10 kernel (fallback tiers)
template <int KDIM, int AGGR>
__global__ __launch_bounds__(512, 6) void mlp_v10_kernel(
    const unsigned short* __restrict__ s0, const int* __restrict__ i0,
    const unsigned short* __restrict__ s1, const int* __restrict__ i1,
    const float* __restrict__ s2,
    const unsigned short* __restrict__ Wb,
    const float* __restrict__ bias, const float* __restrict__ gamma,
    const float* __restrict__ beta,
    const float* __restrict__ resid,
    float* __restrict__ outp,
    void* aggr, const int* __restrict__ aggr_idx,
    const int* __restrict__ prank,
    int M) {
  __shared__ __align__(16) unsigned short smem[16384];
  mlp_core<KDIM, AGGR>(smem, s0, i0, s1, i1, s2, Wb, bias, gamma, beta,
                       resid, outp, aggr, aggr_idx, prank, M, blockIdx.x);
}

// ---------------------------------------------------------------------------
// fused edge + sender launch: blocks [0,gridE) run the edge MLP (K=384,
// writes edge_out + P rows at rank[e]); blocks [gridE, gridE+gridS) run the
// sender MLP (K=128). Independent outputs; sender work overlaps edge latency.
// ---------------------------------------------------------------------------
__global__ __launch_bounds__(512, 6) void fused_es_kernel(
    const unsigned short* __restrict__ sender_b, const int* __restrict__ src,
    const unsigned short* __restrict__ receiver_b, const int* __restrict__ dst,
    const float* __restrict__ edge_attr,
    const unsigned short* __restrict__ We_b,
    const float* __restrict__ be, const float* __restrict__ ge,
    const float* __restrict__ bbe,
    float* __restrict__ edge_out,
    unsigned short* __restrict__ P, const int* __restrict__ rank,
    const unsigned short* __restrict__ Ws_b,
    const float* __restrict__ bs, const float* __restrict__ gs,
    const float* __restrict__ bbs,
    const float* __restrict__ sender_x, float* __restrict__ sender_out,
    int E, int NS, int gridE) {
  __shared__ __align__(16) unsigned short smem[16384];
  const int b = blockIdx.x;
  if (b < gridE) {
    mlp_core<384, 3>(smem, sender_b, src, receiver_b, dst, edge_attr,
                     We_b, be, ge, bbe, edge_attr, edge_out,
                     P, nullptr, rank, E, b);
  } else {
    mlp_core<128, 0>(smem, sender_b, nullptr, nullptr, nullptr, nullptr,
                     Ws_b, bs, gs, bbs, sender_x, sender_out,
                     nullptr, nullptr, nullptr, NS, b - gridE);
  }
}

// ---------------------------------------------------------------------------
// node MLP with fused CSR segment-sum: seg0 = receiver_b row; seg1 fragments
// are the f32 sum of this row's contiguous P slice [offs[r], offs[r]+cnt).
// ---------------------------------------------------------------------------
__global__ __launch_bounds__(512, 4) void node_csr_kernel(
    const unsigned short* __restrict__ s0,           // receiver_b
    const unsigned short* __restrict__ P,
    const int* __restrict__ offs, const int* __restrict__ counts,
    const unsigned short* __restrict__ Wb,           // 2 panels (Wn)
    const float* __restrict__ bias, const float* __restrict__ gamma,
    const float* __restrict__ beta,
    const float* __restrict__ resid, float* __restrict__ outp,
    int M) {
  __shared__ __align__(16) unsigned short smem[16384];

  const int tid = threadIdx.x;
  const int wid = tid >> 6;
  const int lane = tid & 63;
  const int l15 = lane & 15;
  const int q = lane >> 4;
  const int l31 = lane & 31;
  const int rhalf = lane >> 5;
  const int wrow = blockIdx.x * 128 + wid * 16;
  const int xm = l15 << 3;

  int rr = wrow + l15;
  if (rr >= M) rr = M - 1;
  const unsigned short* p0 = s0 + (size_t)rr * 128;

  auto stageB = [&](int seg) {
    const unsigned short* g = Wb + seg * 16384 + wid * 2048 + lane * 8;
    unsigned short* l = &smem[wid * 2048];
    #pragma unroll
    for (int u = 0; u < 4; ++u) {
      __builtin_amdgcn_global_load_lds(
          (const __attribute__((address_space(1))) unsigned int*)(g + u * 512),
          (__attribute__((address_space(3))) unsigned int*)(l + u * 512),
          16, 0, 0);
    }
  };

  U16B Ac[4];
  #pragma unroll
  for (int k4 = 0; k4 < 4; ++k4)
    Ac[k4].u = *reinterpret_cast<const uint4*>(p0 + k4 * 32 + q * 8);

  stageB(0);
  __syncthreads();                 // B0 staged

  f32x4 acc[8] = {};
  #pragma unroll
  for (int k4 = 0; k4 < 4; ++k4) {
    #pragma unroll
    for (int n = 0; n < 8; ++n) {
      U16B b;
      b.u = *reinterpret_cast<const uint4*>(
          &smem[(n * 16 + l15) * 128 + ((k4 * 32 + q * 8) ^ xm)]);
      acc[n] = __builtin_amdgcn_mfma_f32_16x16x32_bf16(Ac[k4].v, b.v, acc[n], 0, 0, 0);
    }
  }
  __syncthreads();                 // buffer reads done
  stageB(1);                       // stage Wn panel 1 (in flight over CSR sum)

  // CSR segment-sum -> seg1 fragments (f32 accumulate, bf16 fragments)
  {
    int beg = offs[rr];
    int cnt = counts[rr];
    float a32[32];
    #pragma unroll
    for (int t = 0; t < 32; ++t) a32[t] = 0.f;
    const unsigned short* prow = P + (size_t)beg * 128;
    for (int k = 0; k < cnt; ++k) {
      #pragma unroll
      for (int k4 = 0; k4 < 4; ++k4) {
        uint4 w = *reinterpret_cast<const uint4*>(prow + k4 * 32 + q * 8);
        a32[k4 * 8 + 0] += bfu2f(w.x & 0xffffu);
        a32[k4 * 8 + 1] += bfu2f(w.x >> 16);
        a32[k4 * 8 + 2] += bfu2f(w.y & 0xffffu);
        a32[k4 * 8 + 3] += bfu2f(w.y >> 16);
        a32[k4 * 8 + 4] += bfu2f(w.z & 0xffffu);
        a32[k4 * 8 + 5] += bfu2f(w.z >> 16);
        a32[k4 * 8 + 6] += bfu2f(w.w & 0xffffu);
        a32[k4 * 8 + 7] += bfu2f(w.w >> 16);
      }
      prow += 128;
    }
    #pragma unroll
    for (int k4 = 0; k4 < 4; ++k4) {
      #pragma unroll
      for (int j = 0; j < 8; ++j)
        Ac[k4].v[j] = (__bf16)a32[k4 * 8 + j];
    }
  }
  __syncthreads();                 // B1 staged

  #pragma unroll
  for (int k4 = 0; k4 < 4; ++k4) {
    #pragma unroll
    for (int n = 0; n < 8; ++n) {
      U16B b;
      b.u = *reinterpret_cast<const uint4*>(
          &smem[(n * 16 + l15) * 128 + ((k4 * 32 + q * 8) ^ xm)]);
      acc[n] = __builtin_amdgcn_mfma_f32_16x16x32_bf16(Ac[k4].v, b.v, acc[n], 0, 0, 0);
    }
  }
  __syncthreads();                 // protect epilogue overlay

  // ---- epilogue (v10 2-pass transpose) ----
  float bia[8];
  #pragma unroll
  for (int n = 0; n < 8; ++n) bia[n] = bias[n * 16 + l15];

  float sum[4] = {0.f, 0.f, 0.f, 0.f};
  float ssq[4] = {0.f, 0.f, 0.f, 0.f};
  #pragma unroll
  for (int n = 0; n < 8; ++n) {
    #pragma unroll
    for (int j = 0; j < 4; ++j) {
      float t = silu_f(silu_f(acc[n][j] + bia[n]));
      acc[n][j] = t;
      sum[j] += t;
      ssq[j] += t * t;
    }
  }
  #pragma unroll
  for (int off = 1; off < 16; off <<= 1) {
    #pragma unroll
    for (int j = 0; j < 4; ++j) {
      sum[j] += __shfl_xor(sum[j], off);
      ssq[j] += __shfl_xor(ssq[j], off);
    }
  }
  float mu[4], rs[4];
  #pragma unroll
  for (int j = 0; j < 4; ++j) {
    mu[j] = sum[j] * (1.0f / 128.0f);
    float var = ssq[j] * (1.0f / 128.0f) - mu[j] * mu[j];
    rs[j] = rsqrtf(var + 1e-5f);
  }
  float gam[8], bet[8];
  #pragma unroll
  for (int n = 0; n < 8; ++n) {
    gam[n] = gamma[n * 16 + l15];
    bet[n] = beta[n * 16 + l15];
  }

  unsigned short* yw = &smem[wid * 2048];

  #pragma unroll
  for (int h = 0; h < 2; ++h) {
    if (h == 1) {
      asm volatile("s_waitcnt lgkmcnt(0)" ::: "memory");
    }
    if ((q >> 1) == h) {
      #pragma unroll
      for (int n = 0; n < 8; ++n) {
        #pragma unroll
        for (int j = 0; j < 4; ++j) {
          float y = (acc[n][j] - mu[j]) * rs[j] * gam[n] + bet[n];
          BF1 c; c.h = (__bf16)y;
          yw[((q & 1) * 4 + j) * 132 + n * 16 + l15] = c.s;
        }
      }
    }
    asm volatile("s_waitcnt lgkmcnt(0)" ::: "memory");

    #pragma unroll
    for (int s = 0; s < 4; ++s) {
      int row8 = 2 * s + rhalf;
      int grow = wrow + 8 * h + row8;
      uint2 w = *reinterpret_cast<const uint2*>(&yw[row8 * 132 + l31 * 4]);
      if (grow < M) {
        const f32x4 r4 = *reinterpret_cast<const f32x4*>(resid + (size_t)grow * 128 + l31 * 4);
        f32x4 o4;
        o4.x = r4.x + bfu2f(w.x & 0xffffu);
        o4.y = r4.y + bfu2f(w.x >> 16);
        o4.z = r4.z + bfu2f(w.y & 0xffffu);
        o4.w = r4.w + bfu2f(w.y >> 16);
        __builtin_nontemporal_store(o4, reinterpret_cast<f32x4*>(outp + (size_t)grow * 128 + l31 * 4));
      }
    }
  }
}

// ---------------------------------------------------------------------------
// fallback kernel (fp32 features, fp32 atomics) for small-ws tier.
// ---------------------------------------------------------------------------
template <int KDIM>
__global__ __launch_bounds__(512, 4) void mlp_fb_kernel(
    const float* __restrict__ s0, const int* __restrict__ i0,
    const float* __restrict__ s1, const int* __restrict__ i1,
    const float* __restrict__ s2,
    const unsigned short* __restrict__ Wb,
    const float* __restrict__ bias, const float* __restrict__ gamma,
    const float* __restrict__ beta,
    const float* __restrict__ resid,
    float* __restrict__ outp,
    float* aggr, const int* __restrict__ aggr_idx,
    int M) {
  constexpr int NSEG = KDIM / 128;
  __shared__ __align__(16) unsigned short smem[2][16384];
  const int tid = threadIdx.x;
  const int wid = tid >> 6;
  const int lane = tid & 63;
  const int l15 = lane & 15;
  const int q = lane >> 4;
  const int l31 = lane & 31;
  const int rhalf = lane >> 5;
  const int wrow = blockIdx.x * 128 + wid * 16;
  const int xm = l15 << 3;

  int rr = wrow + l15;
  if (rr >= M) rr = M - 1;
  const float* p0 = s0 + (size_t)(i0 ? i0[rr] : rr) * 128;
  const float* p1 = (KDIM >= 256) ? (s1 + (size_t)(i1 ? i1[rr] : rr) * 128) : nullptr;
  const float* p2 = (KDIM >= 384) ? (s2 + (size_t)rr * 128) : nullptr;

  auto stageB = [&](int seg, int buf) {
    const unsigned short* g = Wb + seg * 16384 + wid * 2048 + lane * 8;
    unsigned short* l = &smem[buf][wid * 2048];
    #pragma unroll
    for (int u = 0; u < 4; ++u) {
      __builtin_amdgcn_global_load_lds(
          (const __attribute__((address_space(1))) unsigned int*)(g + u * 512),
          (__attribute__((address_space(3))) unsigned int*)(l + u * 512),
          16, 0, 0);
    }
  };

  stageB(0, 0);
  f32x4 acc[8] = {};
  __syncthreads();
  int cur = 0;
  #pragma unroll
  for (int seg = 0; seg < NSEG; ++seg) {
    if (seg + 1 < NSEG) stageB(seg + 1, cur ^ 1);
    const float* base = (seg == 0) ? p0 : ((seg == 1) ? p1 : p2);
    #pragma unroll
    for (int k4 = 0; k4 < 4; ++k4) {
      const float4* pp = reinterpret_cast<const float4*>(base + k4 * 32 + q * 8);
      U16B a; a.v = cvt8(pp[0], pp[1]);
      #pragma unroll
      for (int n = 0; n < 8; ++n) {
        U16B b;
        b.u = *reinterpret_cast<const uint4*>(
            &smem[cur][(n * 16 + l15) * 128 + ((k4 * 32 + q * 8) ^ xm)]);
        acc[n] = __builtin_amdgcn_mfma_f32_16x16x32_bf16(a.v, b.v, acc[n], 0, 0, 0);
      }
    }
    __syncthreads();
    if (seg + 1 < NSEG) cur ^= 1;
  }

  unsigned short* yw = &smem[0][0] + wid * (16 * 132);
  float bia[8];
  #pragma unroll
  for (int n = 0; n < 8; ++n) bia[n] = bias[n * 16 + l15];
  float sum[4] = {0.f, 0.f, 0.f, 0.f}, ssq[4] = {0.f, 0.f, 0.f, 0.f};
  #pragma unroll
  for (int n = 0; n < 8; ++n)
    #pragma unroll
    for (int j = 0; j < 4; ++j) {
      float t = silu_f(silu_f(acc[n][j] + bia[n]));
      acc[n][j] = t; sum[j] += t; ssq[j] += t * t;
    }
  #pragma unroll
  for (int off = 1; off < 16; off <<= 1)
    #pragma unroll
    for (int j = 0; j < 4; ++j) {
      sum[j] += __shfl_xor(sum[j], off);
      ssq[j] += __shfl_xor(ssq[j], off);
    }
  float mu[4], rs[4];
  #pragma unroll
  for (int j = 0; j < 4; ++j) {
    mu[j] = sum[j] * (1.0f / 128.0f);
    float var = ssq[j] * (1.0f / 128.0f) - mu[j] * mu[j];
    rs[j] = rsqrtf(var + 1e-5f);
  }
  float gam[8], bet[8];
  #pragma unroll
  for (int n = 0; n < 8; ++n) { gam[n] = gamma[n * 16 + l15]; bet[n] = beta[n * 16 + l15]; }
  #pragma unroll
  for (int n = 0; n < 8; ++n)
    #pragma unroll
    for (int j = 0; j < 4; ++j) {
      float y = (acc[n][j] - mu[j]) * rs[j] * gam[n] + bet[n];
      BF1 c; c.h = (__bf16)y;
      yw[(q * 4 + j) * 132 + n * 16 + l15] = c.s;
    }
  asm volatile("s_waitcnt lgkmcnt(0)" ::: "memory");
  #pragma unroll
  for (int s = 0; s < 8; ++s) {
    int row16 = 2 * s + rhalf;
    int grow = wrow + row16;
    uint2 w = *reinterpret_cast<const uint2*>(&yw[row16 * 132 + l31 * 4]);
    if (grow < M) {
      const f32x4 r4 = *reinterpret_cast<const f32x4*>(resid + (size_t)grow * 128 + l31 * 4);
      f32x4 o4;
      o4.x = r4.x + bfu2f(w.x & 0xffffu);
      o4.y = r4.y + bfu2f(w.x >> 16);
      o4.z = r4.z + bfu2f(w.y & 0xffffu);
      o4.w = r4.w + bfu2f(w.y >> 16);
      __builtin_nontemporal_store(o4, reinterpret_cast<f32x4*>(outp + (size_t)grow * 128 + l31 * 4));
      if (aggr) {
        int idx = aggr_idx[grow];
        float* ar = aggr + (size_t)idx * 128 + l31 * 4;
        atomicAdd(ar + 0, bfu2f(w.x & 0xffffu));
        atomicAdd(ar + 1, bfu2f(w.x >> 16));
        atomicAdd(ar + 2, bfu2f(w.y & 0xffffu));
        atomicAdd(ar + 3, bfu2f(w.y >> 16));
      }
    }
  }
}

extern "C" void kernel_launch(void* const* d_in, const int* in_sizes, int n_in,
                              void* d_out, int out_size, void* d_ws, size_t ws_size,
                              hipStream_t stream) {
  const float* sender_x   = (const float*)d_in[0];
  const float* receiver_x = (const float*)d_in[1];
  const int*   edge_index = (const int*)d_in[2];
  const float* edge_attr  = (const float*)d_in[3];
  const float* We  = (const float*)d_in[4];
  const float* be  = (const float*)d_in[5];
  const float* ge  = (const float*)d_in[6];
  const float* bbe = (const float*)d_in[7];
  const float* Wn  = (const float*)d_in[8];
  const float* bn  = (const float*)d_in[9];
  const float* gn  = (const float*)d_in[10];
  const float* bbn = (const float*)d_in[11];
  const float* Ws  = (const float*)d_in[12];
  const float* bs  = (const float*)d_in[13];
  const float* gs  = (const float*)d_in[14];
  const float* bbs = (const float*)d_in[15];

  const int D  = 128;
  const int NS = in_sizes[0] / D;
  const int NR = in_sizes[1] / D;
  const int E  = in_sizes[2] / 2;

  const int* src = edge_index;
  const int* dst = edge_index + E;

  float* out          = (float*)d_out;
  float* sender_out   = out;
  float* receiver_out = out + (size_t)NS * D;
  float* edge_out     = out + (size_t)(NS + NR) * D;

  const size_t welems = 6 * 16384;
  unsigned short* We_b = (unsigned short*)d_ws;          // panels 0..2
  unsigned short* Wn_b = We_b + 3 * 16384;               // panels 3..4
  unsigned short* Ws_b = We_b + 5 * 16384;               // panel 5
  unsigned short* sender_b   = We_b + welems;
  unsigned short* receiver_b = sender_b + (size_t)NS * D;
  unsigned short* aggr_b     = receiver_b + (size_t)NR * D;  // tier-1 only
  unsigned short* P_b        = aggr_b + (size_t)NR * D;
  int* counts    = (int*)(P_b + (size_t)E * D);
  int* pre       = counts + NR;
  int* offs      = pre + NR;
  int* cursor    = offs + NR;
  int* blockSums = cursor + NR;
  int* rank      = blockSums + 512;

  const int nScanBlocks = (NR + 1023) / 1024;
  const size_t needCSR = 2 * (welems + (size_t)(NS + 2 * NR) * D + (size_t)E * D)
                       + 4 * (4 * (size_t)NR + 512 + (size_t)E);
  const size_t needA = (welems + (size_t)(NS + 2 * NR) * D) * 2;

  int tier;
  if (ws_size >= needCSR && nScanBlocks <= 512) tier = 0;
  else if (ws_size >= needA) tier = 1;
  else tier = 2;

  const int gridE = (E + 127) / 128;
  const int gridR = (NR + 127) / 128;
  const int gridS = (NS + 127) / 128;
  const int n8s = NS * D / 8, n8r = NR * D / 8;

  if (tier == 0) {
    (void)hipMemsetAsync(counts, 0, (size_t)NR * 4, stream);
    const int prepItems = (int)welems + n8s + n8r + E;
    prep_kernel<<<(prepItems + 255) / 256, 256, 0, stream>>>(
        We, Wn, Ws, We_b, sender_x, sender_b, receiver_x, receiver_b,
        n8s, n8r, dst, counts, E);

    scan1_kernel<<<nScanBlocks, 256, 0, stream>>>(counts, pre, blockSums, NR);
    scan2_kernel<<<1, 512, 0, stream>>>(blockSums, nScanBlocks);
    scan3_kernel<<<(NR + 255) / 256, 256, 0, stream>>>(pre, blockSums, offs, cursor, NR);
    scatter_kernel<<<(E + 255) / 256, 256, 0, stream>>>(dst, cursor, rank, E);

    // edge MLP + sender MLP in one launch (independent work overlaps)
    fused_es_kernel<<<gridE + gridS, 512, 0, stream>>>(
        sender_b, src, receiver_b, dst, edge_attr,
        We_b, be, ge, bbe, edge_out, P_b, rank,
        Ws_b, bs, gs, bbs, sender_x, sender_out,
        E, NS, gridE);

    // node MLP with fused CSR segment-sum
    node_csr_kernel<<<gridR, 512, 0, stream>>>(
        receiver_b, P_b, offs, counts,
        Wn_b, bn, gn, bbn, receiver_x, receiver_out, NR);
  } else if (tier == 1) {
    const int prepItems = (int)welems + n8s + n8r;
    prep_kernel<<<(prepItems + 255) / 256, 256, 0, stream>>>(
        We, Wn, Ws, We_b, sender_x, sender_b, receiver_x, receiver_b,
        n8s, n8r, nullptr, nullptr, 0);
    (void)hipMemsetAsync(aggr_b, 0, (size_t)NR * D * 2, stream);

    mlp_v10_kernel<384, 2><<<gridE, 512, 0, stream>>>(
        sender_b, src, receiver_b, dst, edge_attr,
        We_b, be, ge, bbe, edge_attr, edge_out, aggr_b, dst, nullptr, E);

    mlp_v10_kernel<256, 0><<<gridR, 512, 0, stream>>>(
        receiver_b, nullptr, aggr_b, nullptr, nullptr,
        Wn_b, bn, gn, bbn, receiver_x, receiver_out, nullptr, nullptr, nullptr, NR);

    mlp_v10_kernel<128, 0><<<gridS, 512, 0, stream>>>(
        sender_b, nullptr, nullptr, nullptr, nullptr,
        Ws_b, bs, gs, bbs, sender_x, sender_out, nullptr, nullptr, nullptr, NS);
  } else {
    prep_kernel<<<(int)((welems + 255) / 256), 256, 0, stream>>>(
        We, Wn, Ws, We_b, nullptr, nullptr, nullptr, nullptr, 0, 0,
        nullptr, nullptr, 0);
    (void)hipMemsetAsync(receiver_out, 0, (size_t)NR * D * sizeof(float), stream);

    mlp_fb_kernel<384><<<gridE, 512, 0, stream>>>(
        sender_x, src, receiver_x, dst, edge_attr,
        We_b, be, ge, bbe, edge_attr, edge_out, receiver_out, dst, E);

    mlp_fb_kernel<256><<<gridR, 512, 0, stream>>>(
        receiver_x, nullptr, receiver_out, nullptr, nullptr,
        Wn_b, bn, gn, bbn, receiver_x, receiver_out, nullptr, nullptr, NR);

    mlp_fb_kernel<128><<<gridS, 512, 0, stream>>>(
        sender_x, nullptr, nullptr, nullptr, nullptr,
        Ws_b, bs, gs, bbs, sender_x, sender_out, nullptr, nullptr, NS);
  }
}

// Round 15
// 451.303 us; speedup vs baseline: 1.0373x; 1.0041x over previous
//
#include <hip/hip_runtime.h>
#include <stdint.h>

// ---------------------------------------------------------------------------
// GCastHeterocoder FINAL (= round 12, best known 451 us; round-13 dst-sorted
// variant regressed and is reverted). Structure:
//   prep (swizzled bf16 weight image + bf16 node rows + dst histogram)
//   -> CSR scan/scatter -> fused edge+sender MFMA MLP (rank-placed P rows)
//   -> node MLP with fused CSR segment-sum.
// Empirical roofline: 3.5-3.8 TB/s effective for the stream+random-gather
// access mix, traffic at hand-computed minimum.
// ---------------------------------------------------------------------------

typedef __bf16 bf16x8 __attribute__((ext_vector_type(8)));
typedef float  f32x4  __attribute__((ext_vector_type(4)));

union U16B { uint4 u; bf16x8 v; };
union BFPK { __bf16 h[2]; unsigned int u; };
union BF1  { __bf16 h; unsigned short s; };

__device__ __forceinline__ float silu_f(float x) {
  return x * __builtin_amdgcn_rcpf(1.0f + __expf(-x));
}
__device__ __forceinline__ float bfu2f(unsigned int lo16) {
  return __uint_as_float(lo16 << 16);
}
__device__ __forceinline__ bf16x8 cvt8(float4 a, float4 b) {
  bf16x8 r;
  r[0] = (__bf16)a.x; r[1] = (__bf16)a.y; r[2] = (__bf16)a.z; r[3] = (__bf16)a.w;
  r[4] = (__bf16)b.x; r[5] = (__bf16)b.y; r[6] = (__bf16)b.z; r[7] = (__bf16)b.w;
  return r;
}

// ---------------- fused prep: swizzled weight image + bf16 rows + hist -----
// Weight image: 6 panels [128 r][128 c]; row r byte b holds W[r][(b^((r&15)<<4))/2].
__global__ void prep_kernel(const float* __restrict__ We,
                            const float* __restrict__ Wn,
                            const float* __restrict__ Ws,
                            unsigned short* __restrict__ wimg,
                            const float* __restrict__ sx,
                            unsigned short* __restrict__ sb,
                            const float* __restrict__ rx,
                            unsigned short* __restrict__ rb,
                            int n8s, int n8r,
                            const int* __restrict__ dst,
                            int* __restrict__ counts, int E) {
  int i = blockIdx.x * 256 + threadIdx.x;
  if (i < 6 * 16384) {
    int panel = i >> 14;
    int r = (i >> 7) & 127;
    int csw = i & 127;
    int c_or = ((csw * 2) ^ ((r & 15) << 4)) >> 1;
    float f;
    if (panel < 3)      f = We[r * 384 + panel * 128 + c_or];
    else if (panel < 5) f = Wn[r * 256 + (panel - 3) * 128 + c_or];
    else                f = Ws[r * 128 + c_or];
    BF1 c; c.h = (__bf16)f;
    wimg[i] = c.s;
    return;
  }
  int j = i - 6 * 16384;
  if (j < n8s + n8r) {
    const float* in; unsigned short* out; int idx;
    if (j < n8s) { in = sx; out = sb; idx = j; }
    else         { in = rx; out = rb; idx = j - n8s; }
    float4 a = reinterpret_cast<const float4*>(in)[2 * idx];
    float4 b = reinterpret_cast<const float4*>(in)[2 * idx + 1];
    U16B r8; r8.v = cvt8(a, b);
    reinterpret_cast<uint4*>(out)[idx] = r8.u;
    return;
  }
  int e = j - n8s - n8r;
  if (e < E) atomicAdd(&counts[dst[e]], 1);
}

// ---------------- CSR build ----------------
__global__ void scan1_kernel(const int* __restrict__ counts, int* __restrict__ pre,
                             int* __restrict__ blockSums, int n) {
  __shared__ int sh[256];
  const int t = threadIdx.x;
  const int base = blockIdx.x * 1024 + t * 4;
  int c0 = (base + 0 < n) ? counts[base + 0] : 0;
  int c1 = (base + 1 < n) ? counts[base + 1] : 0;
  int c2 = (base + 2 < n) ? counts[base + 2] : 0;
  int c3 = (base + 3 < n) ? counts[base + 3] : 0;
  int tot = c0 + c1 + c2 + c3;
  sh[t] = tot;
  __syncthreads();
  #pragma unroll
  for (int off = 1; off < 256; off <<= 1) {
    int v = (t >= off) ? sh[t - off] : 0;
    __syncthreads();
    sh[t] += v;
    __syncthreads();
  }
  int excl = sh[t] - tot;
  if (base + 0 < n) pre[base + 0] = excl;
  if (base + 1 < n) pre[base + 1] = excl + c0;
  if (base + 2 < n) pre[base + 2] = excl + c0 + c1;
  if (base + 3 < n) pre[base + 3] = excl + c0 + c1 + c2;
  if (t == 255) blockSums[blockIdx.x] = sh[255];
}

__global__ void scan2_kernel(int* __restrict__ blockSums, int nb) {
  __shared__ int sh[512];
  const int t = threadIdx.x;
  int v = (t < nb) ? blockSums[t] : 0;
  sh[t] = v;
  __syncthreads();
  #pragma unroll
  for (int off = 1; off < 512; off <<= 1) {
    int u = (t >= off) ? sh[t - off] : 0;
    __syncthreads();
    sh[t] += u;
    __syncthreads();
  }
  if (t < nb) blockSums[t] = sh[t] - v;
}

__global__ void scan3_kernel(const int* __restrict__ pre, const int* __restrict__ blockSums,
                             int* __restrict__ offs, int* __restrict__ cursor, int n) {
  int i = blockIdx.x * 256 + threadIdx.x;
  if (i >= n) return;
  int o = pre[i] + blockSums[i >> 10];
  offs[i] = o;
  cursor[i] = o;
}

// rank[e] = sorted position of edge e (dst-sorted)
__global__ void scatter_kernel(const int* __restrict__ dst, int* __restrict__ cursor,
                               int* __restrict__ rank, int E) {
  int i = blockIdx.x * 256 + threadIdx.x;
  if (i < E) {
    int p = atomicAdd(&cursor[dst[i]], 1);
    rank[i] = p;
  }
}

// ---------------------------------------------------------------------------
// v10 MLP core as a device function (smem passed in; bid replaces blockIdx).
// AGGR: 0=none, 2=pk bf16 atomics, 3=P row at prank[grow].
// ---------------------------------------------------------------------------
template <int KDIM, int AGGR>
__device__ __forceinline__ void mlp_core(
    unsigned short* smem,
    const unsigned short* __restrict__ s0, const int* __restrict__ i0,
    const unsigned short* __restrict__ s1, const int* __restrict__ i1,
    const float* __restrict__ s2,
    const unsigned short* __restrict__ Wb,
    const float* __restrict__ bias, const float* __restrict__ gamma,
    const float* __restrict__ beta,
    const float* __restrict__ resid,
    float* __restrict__ outp,
    void* aggr, const int* __restrict__ aggr_idx,
    const int* __restrict__ prank,
    int M, int bid) {
  constexpr int NSEG = KDIM / 128;

  const int tid = threadIdx.x;
  const int wid = tid >> 6;
  const int lane = tid & 63;
  const int l15 = lane & 15;
  const int q = lane >> 4;
  const int l31 = lane & 31;
  const int rhalf = lane >> 5;
  const int wrow = bid * 128 + wid * 16;
  const int xm = l15 << 3;

  int rr = wrow + l15;
  if (rr >= M) rr = M - 1;
  const unsigned short* p0 = s0 + (size_t)(i0 ? i0[rr] : rr) * 128;
  const unsigned short* p1 = nullptr;
  const float* p2 = nullptr;
  if constexpr (KDIM >= 256) p1 = s1 + (size_t)(i1 ? i1[rr] : rr) * 128;
  if constexpr (KDIM >= 384) p2 = s2 + (size_t)rr * 128;

  auto stageB = [&](int seg) {
    const unsigned short* g = Wb + seg * 16384 + wid * 2048 + lane * 8;
    unsigned short* l = &smem[wid * 2048];
    #pragma unroll
    for (int u = 0; u < 4; ++u) {
      __builtin_amdgcn_global_load_lds(
          (const __attribute__((address_space(1))) unsigned int*)(g + u * 512),
          (__attribute__((address_space(3))) unsigned int*)(l + u * 512),
          16, 0, 0);
    }
  };

  U16B Ac[4], An[4];
  auto loadA = [&](int seg, U16B (&dst)[4]) {
    #pragma unroll
    for (int k4 = 0; k4 < 4; ++k4) {
      const int kof = k4 * 32 + q * 8;
      if (seg == 0) {
        dst[k4].u = *reinterpret_cast<const uint4*>(p0 + kof);
      } else if (seg == 1) {
        dst[k4].u = *reinterpret_cast<const uint4*>(p1 + kof);
      } else {
        const float4* p = reinterpret_cast<const float4*>(p2 + kof);
        dst[k4].v = cvt8(p[0], p[1]);
      }
    }
  };

  f32x4 acc[8] = {};

  stageB(0);
  loadA(0, Ac);
  __syncthreads();

  #pragma unroll
  for (int seg = 0; seg < NSEG; ++seg) {
    if (seg + 1 < NSEG) loadA(seg + 1, An);
    #pragma unroll
    for (int k4 = 0; k4 < 4; ++k4) {
      #pragma unroll
      for (int n = 0; n < 8; ++n) {
        U16B b;
        b.u = *reinterpret_cast<const uint4*>(
            &smem[(n * 16 + l15) * 128 + ((k4 * 32 + q * 8) ^ xm)]);
        acc[n] = __builtin_amdgcn_mfma_f32_16x16x32_bf16(Ac[k4].v, b.v, acc[n], 0, 0, 0);
      }
    }
    __syncthreads();
    if (seg + 1 < NSEG) {
      stageB(seg + 1);
      __syncthreads();
      #pragma unroll
      for (int k4 = 0; k4 < 4; ++k4) Ac[k4] = An[k4];
    }
  }

  float bia[8];
  #pragma unroll
  for (int n = 0; n < 8; ++n) bia[n] = bias[n * 16 + l15];

  float sum[4] = {0.f, 0.f, 0.f, 0.f};
  float ssq[4] = {0.f, 0.f, 0.f, 0.f};
  #pragma unroll
  for (int n = 0; n < 8; ++n) {
    #pragma unroll
    for (int j = 0; j < 4; ++j) {
      float t = silu_f(silu_f(acc[n][j] + bia[n]));
      acc[n][j] = t;
      sum[j] += t;
      ssq[j] += t * t;
    }
  }
  #pragma unroll
  for (int off = 1; off < 16; off <<= 1) {
    #pragma unroll
    for (int j = 0; j < 4; ++j) {
      sum[j] += __shfl_xor(sum[j], off);
      ssq[j] += __shfl_xor(ssq[j], off);
    }
  }
  float mu[4], rs[4];
  #pragma unroll
  for (int j = 0; j < 4; ++j) {
    mu[j] = sum[j] * (1.0f / 128.0f);
    float var = ssq[j] * (1.0f / 128.0f) - mu[j] * mu[j];
    rs[j] = rsqrtf(var + 1e-5f);
  }
  float gam[8], bet[8];
  #pragma unroll
  for (int n = 0; n < 8; ++n) {
    gam[n] = gamma[n * 16 + l15];
    bet[n] = beta[n * 16 + l15];
  }

  unsigned short* yw = &smem[wid * 2048];

  #pragma unroll
  for (int h = 0; h < 2; ++h) {
    if (h == 1) {
      asm volatile("s_waitcnt lgkmcnt(0)" ::: "memory");
    }
    if ((q >> 1) == h) {
      #pragma unroll
      for (int n = 0; n < 8; ++n) {
        #pragma unroll
        for (int j = 0; j < 4; ++j) {
          float y = (acc[n][j] - mu[j]) * rs[j] * gam[n] + bet[n];
          BF1 c; c.h = (__bf16)y;
          yw[((q & 1) * 4 + j) * 132 + n * 16 + l15] = c.s;
        }
      }
    }
    asm volatile("s_waitcnt lgkmcnt(0)" ::: "memory");

    #pragma unroll
    for (int s = 0; s < 4; ++s) {
      int row8 = 2 * s + rhalf;
      int grow = wrow + 8 * h + row8;
      uint2 w = *reinterpret_cast<const uint2*>(&yw[row8 * 132 + l31 * 4]);
      if (grow < M) {
        const f32x4 r4 = *reinterpret_cast<const f32x4*>(resid + (size_t)grow * 128 + l31 * 4);
        f32x4 o4;
        o4.x = r4.x + bfu2f(w.x & 0xffffu);
        o4.y = r4.y + bfu2f(w.x >> 16);
        o4.z = r4.z + bfu2f(w.y & 0xffffu);
        o4.w = r4.w + bfu2f(w.y >> 16);
        __builtin_nontemporal_store(o4, reinterpret_cast<f32x4*>(outp + (size_t)grow * 128 + l31 * 4));
        if constexpr (AGGR == 3) {
          int prow = prank[grow];
          *reinterpret_cast<uint2*>((unsigned short*)aggr + (size_t)prow * 128 + l31 * 4) = w;
        } else if constexpr (AGGR == 2) {
          int idx = aggr_idx[grow];
          unsigned short* ar = (unsigned short*)aggr + (size_t)idx * 128 + l31 * 4;
          asm volatile("global_atomic_pk_add_bf16 %0, %1, off" :: "v"(ar), "v"(w.x) : "memory");
          asm volatile("global_atomic_pk_add_bf16 %0, %1, off" :: "v"(ar + 2), "v"(w.y) : "memory");
        }
      }
    }
  }
}

// standalone v10 kernel (fallback tiers)
template <int KDIM, int AGGR>
__global__ __launch_bounds__(512, 6) void mlp_v10_kernel(
    const unsigned short* __restrict__ s0, const int* __restrict__ i0,
    const unsigned short* __restrict__ s1, const int* __restrict__ i1,
    const float* __restrict__ s2,
    const unsigned short* __restrict__ Wb,
    const float* __restrict__ bias, const float* __restrict__ gamma,
    const float* __restrict__ beta,
    const float* __restrict__ resid,
    float* __restrict__ outp,
    void* aggr, const int* __restrict__ aggr_idx,
    const int* __restrict__ prank,
    int M) {
  __shared__ __align__(16) unsigned short smem[16384];
  mlp_core<KDIM, AGGR>(smem, s0, i0, s1, i1, s2, Wb, bias, gamma, beta,
                       resid, outp, aggr, aggr_idx, prank, M, blockIdx.x);
}

// ---------------------------------------------------------------------------
// fused edge + sender launch: blocks [0,gridE) run the edge MLP (K=384,
// writes edge_out + P rows at rank[e]); blocks [gridE, gridE+gridS) run the
// sender MLP (K=128). Independent outputs; sender work overlaps edge latency.
// ---------------------------------------------------------------------------
__global__ __launch_bounds__(512, 6) void fused_es_kernel(
    const unsigned short* __restrict__ sender_b, const int* __restrict__ src,
    const unsigned short* __restrict__ receiver_b, const int* __restrict__ dst,
    const float* __restrict__ edge_attr,
    const unsigned short* __restrict__ We_b,
    const float* __restrict__ be, const float* __restrict__ ge,
    const float* __restrict__ bbe,
    float* __restrict__ edge_out,
    unsigned short* __restrict__ P, const int* __restrict__ rank,
    const unsigned short* __restrict__ Ws_b,
    const float* __restrict__ bs, const float* __restrict__ gs,
    const float* __restrict__ bbs,
    const float* __restrict__ sender_x, float* __restrict__ sender_out,
    int E, int NS, int gridE) {
  __shared__ __align__(16) unsigned short smem[16384];
  const int b = blockIdx.x;
  if (b < gridE) {
    mlp_core<384, 3>(smem, sender_b, src, receiver_b, dst, edge_attr,
                     We_b, be, ge, bbe, edge_attr, edge_out,
                     P, nullptr, rank, E, b);
  } else {
    mlp_core<128, 0>(smem, sender_b, nullptr, nullptr, nullptr, nullptr,
                     Ws_b, bs, gs, bbs, sender_x, sender_out,
                     nullptr, nullptr, nullptr, NS, b - gridE);
  }
}

// ---------------------------------------------------------------------------
// node MLP with fused CSR segment-sum: seg0 = receiver_b row; seg1 fragments
// are the f32 sum of this row's contiguous P slice [offs[r], offs[r]+cnt).
// ---------------------------------------------------------------------------
__global__ __launch_bounds__(512, 4) void node_csr_kernel(
    const unsigned short* __restrict__ s0,           // receiver_b
    const unsigned short* __restrict__ P,
    const int* __restrict__ offs, const int* __restrict__ counts,
    const unsigned short* __restrict__ Wb,           // 2 panels (Wn)
    const float* __restrict__ bias, const float* __restrict__ gamma,
    const float* __restrict__ beta,
    const float* __restrict__ resid, float* __restrict__ outp,
    int M) {
  __shared__ __align__(16) unsigned short smem[16384];

  const int tid = threadIdx.x;
  const int wid = tid >> 6;
  const int lane = tid & 63;
  const int l15 = lane & 15;
  const int q = lane >> 4;
  const int l31 = lane & 31;
  const int rhalf = lane >> 5;
  const int wrow = blockIdx.x * 128 + wid * 16;
  const int xm = l15 << 3;

  int rr = wrow + l15;
  if (rr >= M) rr = M - 1;
  const unsigned short* p0 = s0 + (size_t)rr * 128;

  auto stageB = [&](int seg) {
    const unsigned short* g = Wb + seg * 16384 + wid * 2048 + lane * 8;
    unsigned short* l = &smem[wid * 2048];
    #pragma unroll
    for (int u = 0; u < 4; ++u) {
      __builtin_amdgcn_global_load_lds(
          (const __attribute__((address_space(1))) unsigned int*)(g + u * 512),
          (__attribute__((address_space(3))) unsigned int*)(l + u * 512),
          16, 0, 0);
    }
  };

  U16B Ac[4];
  #pragma unroll
  for (int k4 = 0; k4 < 4; ++k4)
    Ac[k4].u = *reinterpret_cast<const uint4*>(p0 + k4 * 32 + q * 8);

  stageB(0);
  __syncthreads();                 // B0 staged

  f32x4 acc[8] = {};
  #pragma unroll
  for (int k4 = 0; k4 < 4; ++k4) {
    #pragma unroll
    for (int n = 0; n < 8; ++n) {
      U16B b;
      b.u = *reinterpret_cast<const uint4*>(
          &smem[(n * 16 + l15) * 128 + ((k4 * 32 + q * 8) ^ xm)]);
      acc[n] = __builtin_amdgcn_mfma_f32_16x16x32_bf16(Ac[k4].v, b.v, acc[n], 0, 0, 0);
    }
  }
  __syncthreads();                 // buffer reads done
  stageB(1);                       // stage Wn panel 1 (in flight over CSR sum)

  // CSR segment-sum -> seg1 fragments (f32 accumulate, bf16 fragments)
  {
    int beg = offs[rr];
    int cnt = counts[rr];
    float a32[32];
    #pragma unroll
    for (int t = 0; t < 32; ++t) a32[t] = 0.f;
    const unsigned short* prow = P + (size_t)beg * 128;
    for (int k = 0; k < cnt; ++k) {
      #pragma unroll
      for (int k4 = 0; k4 < 4; ++k4) {
        uint4 w = *reinterpret_cast<const uint4*>(prow + k4 * 32 + q * 8);
        a32[k4 * 8 + 0] += bfu2f(w.x & 0xffffu);
        a32[k4 * 8 + 1] += bfu2f(w.x >> 16);
        a32[k4 * 8 + 2] += bfu2f(w.y & 0xffffu);
        a32[k4 * 8 + 3] += bfu2f(w.y >> 16);
        a32[k4 * 8 + 4] += bfu2f(w.z & 0xffffu);
        a32[k4 * 8 + 5] += bfu2f(w.z >> 16);
        a32[k4 * 8 + 6] += bfu2f(w.w & 0xffffu);
        a32[k4 * 8 + 7] += bfu2f(w.w >> 16);
      }
      prow += 128;
    }
    #pragma unroll
    for (int k4 = 0; k4 < 4; ++k4) {
      #pragma unroll
      for (int j = 0; j < 8; ++j)
        Ac[k4].v[j] = (__bf16)a32[k4 * 8 + j];
    }
  }
  __syncthreads();                 // B1 staged

  #pragma unroll
  for (int k4 = 0; k4 < 4; ++k4) {
    #pragma unroll
    for (int n = 0; n < 8; ++n) {
      U16B b;
      b.u = *reinterpret_cast<const uint4*>(
          &smem[(n * 16 + l15) * 128 + ((k4 * 32 + q * 8) ^ xm)]);
      acc[n] = __builtin_amdgcn_mfma_f32_16x16x32_bf16(Ac[k4].v, b.v, acc[n], 0, 0, 0);
    }
  }
  __syncthreads();                 // protect epilogue overlay

  // ---- epilogue (v10 2-pass transpose) ----
  float bia[8];
  #pragma unroll
  for (int n = 0; n < 8; ++n) bia[n] = bias[n * 16 + l15];

  float sum[4] = {0.f, 0.f, 0.f, 0.f};
  float ssq[4] = {0.f, 0.f, 0.f, 0.f};
  #pragma unroll
  for (int n = 0; n < 8; ++n) {
    #pragma unroll
    for (int j = 0; j < 4; ++j) {
      float t = silu_f(silu_f(acc[n][j] + bia[n]));
      acc[n][j] = t;
      sum[j] += t;
      ssq[j] += t * t;
    }
  }
  #pragma unroll
  for (int off = 1; off < 16; off <<= 1) {
    #pragma unroll
    for (int j = 0; j < 4; ++j) {
      sum[j] += __shfl_xor(sum[j], off);
      ssq[j] += __shfl_xor(ssq[j], off);
    }
  }
  float mu[4], rs[4];
  #pragma unroll
  for (int j = 0; j < 4; ++j) {
    mu[j] = sum[j] * (1.0f / 128.0f);
    float var = ssq[j] * (1.0f / 128.0f) - mu[j] * mu[j];
    rs[j] = rsqrtf(var + 1e-5f);
  }
  float gam[8], bet[8];
  #pragma unroll
  for (int n = 0; n < 8; ++n) {
    gam[n] = gamma[n * 16 + l15];
    bet[n] = beta[n * 16 + l15];
  }

  unsigned short* yw = &smem[wid * 2048];

  #pragma unroll
  for (int h = 0; h < 2; ++h) {
    if (h == 1) {
      asm volatile("s_waitcnt lgkmcnt(0)" ::: "memory");
    }
    if ((q >> 1) == h) {
      #pragma unroll
      for (int n = 0; n < 8; ++n) {
        #pragma unroll
        for (int j = 0; j < 4; ++j) {
          float y = (acc[n][j] - mu[j]) * rs[j] * gam[n] + bet[n];
          BF1 c; c.h = (__bf16)y;
          yw[((q & 1) * 4 + j) * 132 + n * 16 + l15] = c.s;
        }
      }
    }
    asm volatile("s_waitcnt lgkmcnt(0)" ::: "memory");

    #pragma unroll
    for (int s = 0; s < 4; ++s) {
      int row8 = 2 * s + rhalf;
      int grow = wrow + 8 * h + row8;
      uint2 w = *reinterpret_cast<const uint2*>(&yw[row8 * 132 + l31 * 4]);
      if (grow < M) {
        const f32x4 r4 = *reinterpret_cast<const f32x4*>(resid + (size_t)grow * 128 + l31 * 4);
        f32x4 o4;
        o4.x = r4.x + bfu2f(w.x & 0xffffu);
        o4.y = r4.y + bfu2f(w.x >> 16);
        o4.z = r4.z + bfu2f(w.y & 0xffffu);
        o4.w = r4.w + bfu2f(w.y >> 16);
        __builtin_nontemporal_store(o4, reinterpret_cast<f32x4*>(outp + (size_t)grow * 128 + l31 * 4));
      }
    }
  }
}

// ---------------------------------------------------------------------------
// fallback kernel (fp32 features, fp32 atomics) for small-ws tier.
// ---------------------------------------------------------------------------
template <int KDIM>
__global__ __launch_bounds__(512, 4) void mlp_fb_kernel(
    const float* __restrict__ s0, const int* __restrict__ i0,
    const float* __restrict__ s1, const int* __restrict__ i1,
    const float* __restrict__ s2,
    const unsigned short* __restrict__ Wb,
    const float* __restrict__ bias, const float* __restrict__ gamma,
    const float* __restrict__ beta,
    const float* __restrict__ resid,
    float* __restrict__ outp,
    float* aggr, const int* __restrict__ aggr_idx,
    int M) {
  constexpr int NSEG = KDIM / 128;
  __shared__ __align__(16) unsigned short smem[2][16384];
  const int tid = threadIdx.x;
  const int wid = tid >> 6;
  const int lane = tid & 63;
  const int l15 = lane & 15;
  const int q = lane >> 4;
  const int l31 = lane & 31;
  const int rhalf = lane >> 5;
  const int wrow = blockIdx.x * 128 + wid * 16;
  const int xm = l15 << 3;

  int rr = wrow + l15;
  if (rr >= M) rr = M - 1;
  const float* p0 = s0 + (size_t)(i0 ? i0[rr] : rr) * 128;
  const float* p1 = (KDIM >= 256) ? (s1 + (size_t)(i1 ? i1[rr] : rr) * 128) : nullptr;
  const float* p2 = (KDIM >= 384) ? (s2 + (size_t)rr * 128) : nullptr;

  auto stageB = [&](int seg, int buf) {
    const unsigned short* g = Wb + seg * 16384 + wid * 2048 + lane * 8;
    unsigned short* l = &smem[buf][wid * 2048];
    #pragma unroll
    for (int u = 0; u < 4; ++u) {
      __builtin_amdgcn_global_load_lds(
          (const __attribute__((address_space(1))) unsigned int*)(g + u * 512),
          (__attribute__((address_space(3))) unsigned int*)(l + u * 512),
          16, 0, 0);
    }
  };

  stageB(0, 0);
  f32x4 acc[8] = {};
  __syncthreads();
  int cur = 0;
  #pragma unroll
  for (int seg = 0; seg < NSEG; ++seg) {
    if (seg + 1 < NSEG) stageB(seg + 1, cur ^ 1);
    const float* base = (seg == 0) ? p0 : ((seg == 1) ? p1 : p2);
    #pragma unroll
    for (int k4 = 0; k4 < 4; ++k4) {
      const float4* pp = reinterpret_cast<const float4*>(base + k4 * 32 + q * 8);
      U16B a; a.v = cvt8(pp[0], pp[1]);
      #pragma unroll
      for (int n = 0; n < 8; ++n) {
        U16B b;
        b.u = *reinterpret_cast<const uint4*>(
            &smem[cur][(n * 16 + l15) * 128 + ((k4 * 32 + q * 8) ^ xm)]);
        acc[n] = __builtin_amdgcn_mfma_f32_16x16x32_bf16(a.v, b.v, acc[n], 0, 0, 0);
      }
    }
    __syncthreads();
    if (seg + 1 < NSEG) cur ^= 1;
  }

  unsigned short* yw = &smem[0][0] + wid * (16 * 132);
  float bia[8];
  #pragma unroll
  for (int n = 0; n < 8; ++n) bia[n] = bias[n * 16 + l15];
  float sum[4] = {0.f, 0.f, 0.f, 0.f}, ssq[4] = {0.f, 0.f, 0.f, 0.f};
  #pragma unroll
  for (int n = 0; n < 8; ++n)
    #pragma unroll
    for (int j = 0; j < 4; ++j) {
      float t = silu_f(silu_f(acc[n][j] + bia[n]));
      acc[n][j] = t; sum[j] += t; ssq[j] += t * t;
    }
  #pragma unroll
  for (int off = 1; off < 16; off <<= 1)
    #pragma unroll
    for (int j = 0; j < 4; ++j) {
      sum[j] += __shfl_xor(sum[j], off);
      ssq[j] += __shfl_xor(ssq[j], off);
    }
  float mu[4], rs[4];
  #pragma unroll
  for (int j = 0; j < 4; ++j) {
    mu[j] = sum[j] * (1.0f / 128.0f);
    float var = ssq[j] * (1.0f / 128.0f) - mu[j] * mu[j];
    rs[j] = rsqrtf(var + 1e-5f);
  }
  float gam[8], bet[8];
  #pragma unroll
  for (int n = 0; n < 8; ++n) { gam[n] = gamma[n * 16 + l15]; bet[n] = beta[n * 16 + l15]; }
  #pragma unroll
  for (int n = 0; n < 8; ++n)
    #pragma unroll
    for (int j = 0; j < 4; ++j) {
      float y = (acc[n][j] - mu[j]) * rs[j] * gam[n] + bet[n];
      BF1 c; c.h = (__bf16)y;
      yw[(q * 4 + j) * 132 + n * 16 + l15] = c.s;
    }
  asm volatile("s_waitcnt lgkmcnt(0)" ::: "memory");
  #pragma unroll
  for (int s = 0; s < 8; ++s) {
    int row16 = 2 * s + rhalf;
    int grow = wrow + row16;
    uint2 w = *reinterpret_cast<const uint2*>(&yw[row16 * 132 + l31 * 4]);
    if (grow < M) {
      const f32x4 r4 = *reinterpret_cast<const f32x4*>(resid + (size_t)grow * 128 + l31 * 4);
      f32x4 o4;
      o4.x = r4.x + bfu2f(w.x & 0xffffu);
      o4.y = r4.y + bfu2f(w.x >> 16);
      o4.z = r4.z + bfu2f(w.y & 0xffffu);
      o4.w = r4.w + bfu2f(w.y >> 16);
      __builtin_nontemporal_store(o4, reinterpret_cast<f32x4*>(outp + (size_t)grow * 128 + l31 * 4));
      if (aggr) {
        int idx = aggr_idx[grow];
        float* ar = aggr + (size_t)idx * 128 + l31 * 4;
        atomicAdd(ar + 0, bfu2f(w.x & 0xffffu));
        atomicAdd(ar + 1, bfu2f(w.x >> 16));
        atomicAdd(ar + 2, bfu2f(w.y & 0xffffu));
        atomicAdd(ar + 3, bfu2f(w.y >> 16));
      }
    }
  }
}

extern "C" void kernel_launch(void* const* d_in, const int* in_sizes, int n_in,
                              void* d_out, int out_size, void* d_ws, size_t ws_size,
                              hipStream_t stream) {
  const float* sender_x   = (const float*)d_in[0];
  const float* receiver_x = (const float*)d_in[1];
  const int*   edge_index = (const int*)d_in[2];
  const float* edge_attr  = (const float*)d_in[3];
  const float* We  = (const float*)d_in[4];
  const float* be  = (const float*)d_in[5];
  const float* ge  = (const float*)d_in[6];
  const float* bbe = (const float*)d_in[7];
  const float* Wn  = (const float*)d_in[8];
  const float* bn  = (const float*)d_in[9];
  const float* gn  = (const float*)d_in[10];
  const float* bbn = (const float*)d_in[11];
  const float* Ws  = (const float*)d_in[12];
  const float* bs  = (const float*)d_in[13];
  const float* gs  = (const float*)d_in[14];
  const float* bbs = (const float*)d_in[15];

  const int D  = 128;
  const int NS = in_sizes[0] / D;
  const int NR = in_sizes[1] / D;
  const int E  = in_sizes[2] / 2;

  const int* src = edge_index;
  const int* dst = edge_index + E;

  float* out          = (float*)d_out;
  float* sender_out   = out;
  float* receiver_out = out + (size_t)NS * D;
  float* edge_out     = out + (size_t)(NS + NR) * D;

  const size_t welems = 6 * 16384;
  unsigned short* We_b = (unsigned short*)d_ws;          // panels 0..2
  unsigned short* Wn_b = We_b + 3 * 16384;               // panels 3..4
  unsigned short* Ws_b = We_b + 5 * 16384;               // panel 5
  unsigned short* sender_b   = We_b + welems;
  unsigned short* receiver_b = sender_b + (size_t)NS * D;
  unsigned short* aggr_b     = receiver_b + (size_t)NR * D;  // tier-1 only
  unsigned short* P_b        = aggr_b + (size_t)NR * D;
  int* counts    = (int*)(P_b + (size_t)E * D);
  int* pre       = counts + NR;
  int* offs      = pre + NR;
  int* cursor    = offs + NR;
  int* blockSums = cursor + NR;
  int* rank      = blockSums + 512;

  const int nScanBlocks = (NR + 1023) / 1024;
  const size_t needCSR = 2 * (welems + (size_t)(NS + 2 * NR) * D + (size_t)E * D)
                       + 4 * (4 * (size_t)NR + 512 + (size_t)E);
  const size_t needA = (welems + (size_t)(NS + 2 * NR) * D) * 2;

  int tier;
  if (ws_size >= needCSR && nScanBlocks <= 512) tier = 0;
  else if (ws_size >= needA) tier = 1;
  else tier = 2;

  const int gridE = (E + 127) / 128;
  const int gridR = (NR + 127) / 128;
  const int gridS = (NS + 127) / 128;
  const int n8s = NS * D / 8, n8r = NR * D / 8;

  if (tier == 0) {
    (void)hipMemsetAsync(counts, 0, (size_t)NR * 4, stream);
    const int prepItems = (int)welems + n8s + n8r + E;
    prep_kernel<<<(prepItems + 255) / 256, 256, 0, stream>>>(
        We, Wn, Ws, We_b, sender_x, sender_b, receiver_x, receiver_b,
        n8s, n8r, dst, counts, E);

    scan1_kernel<<<nScanBlocks, 256, 0, stream>>>(counts, pre, blockSums, NR);
    scan2_kernel<<<1, 512, 0, stream>>>(blockSums, nScanBlocks);
    scan3_kernel<<<(NR + 255) / 256, 256, 0, stream>>>(pre, blockSums, offs, cursor, NR);
    scatter_kernel<<<(E + 255) / 256, 256, 0, stream>>>(dst, cursor, rank, E);

    // edge MLP + sender MLP in one launch (independent work overlaps)
    fused_es_kernel<<<gridE + gridS, 512, 0, stream>>>(
        sender_b, src, receiver_b, dst, edge_attr,
        We_b, be, ge, bbe, edge_out, P_b, rank,
        Ws_b, bs, gs, bbs, sender_x, sender_out,
        E, NS, gridE);

    // node MLP with fused CSR segment-sum
    node_csr_kernel<<<gridR, 512, 0, stream>>>(
        receiver_b, P_b, offs, counts,
        Wn_b, bn, gn, bbn, receiver_x, receiver_out, NR);
  } else if (tier == 1) {
    const int prepItems = (int)welems + n8s + n8r;
    prep_kernel<<<(prepItems + 255) / 256, 256, 0, stream>>>(
        We, Wn, Ws, We_b, sender_x, sender_b, receiver_x, receiver_b,
        n8s, n8r, nullptr, nullptr, 0);
    (void)hipMemsetAsync(aggr_b, 0, (size_t)NR * D * 2, stream);

    mlp_v10_kernel<384, 2><<<gridE, 512, 0, stream>>>(
        sender_b, src, receiver_b, dst, edge_attr,
        We_b, be, ge, bbe, edge_attr, edge_out, aggr_b, dst, nullptr, E);

    mlp_v10_kernel<256, 0><<<gridR, 512, 0, stream>>>(
        receiver_b, nullptr, aggr_b, nullptr, nullptr,
        Wn_b, bn, gn, bbn, receiver_x, receiver_out, nullptr, nullptr, nullptr, NR);

    mlp_v10_kernel<128, 0><<<gridS, 512, 0, stream>>>(
        sender_b, nullptr, nullptr, nullptr, nullptr,
        Ws_b, bs, gs, bbs, sender_x, sender_out, nullptr, nullptr, nullptr, NS);
  } else {
    prep_kernel<<<(int)((welems + 255) / 256), 256, 0, stream>>>(
        We, Wn, Ws, We_b, nullptr, nullptr, nullptr, nullptr, 0, 0,
        nullptr, nullptr, 0);
    (void)hipMemsetAsync(receiver_out, 0, (size_t)NR * D * sizeof(float), stream);

    mlp_fb_kernel<384><<<gridE, 512, 0, stream>>>(
        sender_x, src, receiver_x, dst, edge_attr,
        We_b, be, ge, bbe, edge_attr, edge_out, receiver_out, dst, E);

    mlp_fb_kernel<256><<<gridR, 512, 0, stream>>>(
        receiver_x, nullptr, receiver_out, nullptr, nullptr,
        Wn_b, bn, gn, bbn, receiver_x, receiver_out, nullptr, nullptr, NR);

    mlp_fb_kernel<128><<<gridS, 512, 0, stream>>>(
        sender_x, nullptr, nullptr, nullptr, nullptr,
        Ws_b, bs, gs, bbs, sender_x, sender_out, nullptr, nullptr, NS);
  }
}